// Round 8
// baseline (520.690 us; speedup 1.0000x reference)
//
#include <hip/hip_runtime.h>
#include <cstdint>

typedef unsigned short u16;
typedef unsigned int   u32;
typedef __bf16 bf16x8 __attribute__((ext_vector_type(8)));
typedef float  f32x4  __attribute__((ext_vector_type(4)));

#define NCTX 10
#define BSZ  32
#define IDF  256
#define QSZ  1024
#define CDF  512
#define LSZ  128

__device__ __forceinline__ u16 f2bf(float f) {
    u32 u = __float_as_uint(f);
    u += 0x7FFFu + ((u >> 16) & 1u);          // RNE to bf16
    return (u16)(u >> 16);
}
__device__ __forceinline__ float bf2f(u16 h) {
    return __uint_as_float(((u32)h) << 16);
}

union U4V { uint4 u; bf16x8 v; };

__device__ __forceinline__ bf16x8 ldg16(const u16* p) {   // 8 contiguous bf16 (16B)
    U4V t; t.u = *(const uint4*)p; return t.v;
}
__device__ __forceinline__ bf16x8 lds16(const u16* p) {   // 8 bf16 from LDS (ds_read_b128)
    U4V t; t.u = *(const uint4*)p; return t.v;
}
__device__ __forceinline__ bf16x8 pack8(const float* f) { // 8 f32 -> bf16x8 (RNE)
    U4V t;
    t.u.x = (u32)f2bf(f[0]) | ((u32)f2bf(f[1]) << 16);
    t.u.y = (u32)f2bf(f[2]) | ((u32)f2bf(f[3]) << 16);
    t.u.z = (u32)f2bf(f[4]) | ((u32)f2bf(f[5]) << 16);
    t.u.w = (u32)f2bf(f[6]) | ((u32)f2bf(f[7]) << 16);
    return t.v;
}
__device__ __forceinline__ f32x4 mfma16(bf16x8 a, bf16x8 b, f32x4 c) {
    return __builtin_amdgcn_mfma_f32_16x16x32_bf16(a, b, c, 0, 0, 0);
}
__device__ __forceinline__ void prio1() { __builtin_amdgcn_s_setprio(1); }
__device__ __forceinline__ void prio0() { __builtin_amdgcn_s_setprio(0); }

// async global->LDS, 16B per lane; LDS dest is wave-uniform base + lane*16
__device__ __forceinline__ void gl_lds16(const u16* g, u16* l) {
    __builtin_amdgcn_global_load_lds(
        (__attribute__((address_space(1))) void*)(g),
        (__attribute__((address_space(3))) void*)(l), 16, 0, 0);
}

// ---- sync primitives (counted-vmcnt pipeline; never drain vm in the k-loop)
__device__ __forceinline__ void vm_wait4() {
    asm volatile("s_waitcnt vmcnt(4)" ::: "memory");
    __builtin_amdgcn_sched_barrier(0);
}
__device__ __forceinline__ void vm_wait2() {
    asm volatile("s_waitcnt vmcnt(2)" ::: "memory");
    __builtin_amdgcn_sched_barrier(0);
}
__device__ __forceinline__ void vm_wait0() {
    asm volatile("s_waitcnt vmcnt(0)" ::: "memory");
    __builtin_amdgcn_sched_barrier(0);
}
__device__ __forceinline__ void mid_bar()  {
    __builtin_amdgcn_s_barrier();
    asm volatile("" ::: "memory");
}
__device__ __forceinline__ void end_bar()  {
    asm volatile("" ::: "memory");
    __builtin_amdgcn_s_barrier();
    asm volatile("" ::: "memory");
}
__device__ __forceinline__ void lg_bar()   {   // LDS-visibility barrier, no vm drain
    asm volatile("s_waitcnt lgkmcnt(0)" ::: "memory");
    __builtin_amdgcn_sched_barrier(0);
    __builtin_amdgcn_s_barrier();
    asm volatile("" ::: "memory");
}

// ---- staging helpers ----
// Tiles row-major [rows][32] bf16 (64B rows), staged in 1KB chunks of 16 rows.
// Bank swizzle (T2 via pre-swizzled SOURCE, m173): LDS slot (L&3) of row
// rr=L>>2 holds global colgroup ((L&3)+(rr>>1))&3. Reader inverts. (8-way
// conflict without it: 21M cycles round 4 -> 7.9M round 6.)
__device__ __forceinline__ int swz_cg(int L) {
    return (((L & 3) + ((L >> 3) & 3)) & 3) * 8;     // element offset of source colgroup
}
__device__ __forceinline__ int swz_off(int row, int quad) {
    return row * 32 + ((quad - (row >> 1)) & 3) * 8; // element offset for reader
}

// ph1 tile: Bh[128][32] at buf[0..4095], Bl[128][32] at buf[4096..8191]
__device__ __forceinline__ void stage_ph1(u16* buf, const u16* sttH, const u16* sttL,
                                          int c0, int w, int L) {
    const int rr = L >> 2, cg = swz_cg(L);
#pragma unroll
    for (int j = 0; j < 4; ++j) {
        const int c = 4 * w + j;                 // 0..15, wave-uniform
        const int hi = (c < 8);
        const int ch = hi ? c : c - 8;
        const u16* src = (hi ? sttH : sttL) + (long)(ch * 16 + rr) * IDF + c0 + cg;
        gl_lds16(src, buf + (hi ? 0 : 4096) + ch * 512);
    }
}

// 256-row tile [256][32] filling a 16KB buffer
__device__ __forceinline__ void stage_256(u16* buf, const u16* gbase, int stride,
                                          int c0, int w, int L) {
    const int rr = L >> 2, cg = swz_cg(L);
#pragma unroll
    for (int j = 0; j < 4; ++j) {
        const int c = 4 * w + j;                 // 0..15
        const u16* src = gbase + (long)(c * 16 + rr) * stride + c0 + cg;
        gl_lds16(src, buf + c * 512);
    }
}

// 128-row tile [128][32] filling an 8KB buffer (k2's B tile): 2 chunks/wave
__device__ __forceinline__ void stage_128(u16* buf, const u16* gbase, int stride,
                                          int c0, int w, int L) {
    const int rr = L >> 2, cg = swz_cg(L);
#pragma unroll
    for (int j = 0; j < 2; ++j) {
        const int c = 2 * w + j;                 // 0..7
        const u16* src = gbase + (long)(c * 16 + rr) * stride + c0 + cg;
        gl_lds16(src, buf + c * 512);
    }
}

// ---------------- K1a: weights -> bf16 (Wc hi/lo, Wcat plain) ----------------
__global__ __launch_bounds__(256) void k1a_conv(const float* __restrict__ Wc,
                                                const float* __restrict__ Wcat,
                                                u16* __restrict__ Wc_hi,
                                                u16* __restrict__ Wc_lo,
                                                u16* __restrict__ Wcat_bf) {
    int i = blockIdx.x * 256 + threadIdx.x;
    if (i < IDF * CDF) {
        float f = Wc[i];
        u16 h = f2bf(f);
        Wc_hi[i] = h;
        Wc_lo[i] = f2bf(f - bf2f(h));
    } else {
        int j = i - IDF * CDF;
        Wcat_bf[j] = f2bf(Wcat[j]);
    }
}

// ---------------- K1b: input [B,idf,Q] -> T_hi/T_lo [B,Q,idf] ----------------
__global__ __launch_bounds__(256) void k1b_tgt(const float* __restrict__ input,
                                               u16* __restrict__ T_hi,
                                               u16* __restrict__ T_lo) {
    __shared__ float ts[64][33];
    const int tid = threadIdx.x;
    const int qt = blockIdx.x, dt = blockIdx.y, b = blockIdx.z;
    {
        const int dl = tid >> 2, q0 = (tid & 3) * 8;
        const float* src = input + ((long)(b * IDF + dt * 64 + dl)) * QSZ + qt * 32 + q0;
        float4 v0 = *(const float4*)src;
        float4 v1 = *(const float4*)(src + 4);
        ts[dl][q0 + 0] = v0.x; ts[dl][q0 + 1] = v0.y;
        ts[dl][q0 + 2] = v0.z; ts[dl][q0 + 3] = v0.w;
        ts[dl][q0 + 4] = v1.x; ts[dl][q0 + 5] = v1.y;
        ts[dl][q0 + 6] = v1.z; ts[dl][q0 + 7] = v1.w;
    }
    __syncthreads();
    {
        const int ql = tid >> 3, d8 = (tid & 7) * 8;
        u16 hi[8], lo[8];
#pragma unroll
        for (int i = 0; i < 8; ++i) {
            float f = ts[d8 + i][ql];
            hi[i] = f2bf(f);
            lo[i] = f2bf(f - bf2f(hi[i]));
        }
        const long o = ((long)(b * QSZ + qt * 32 + ql)) * IDF + dt * 64 + d8;
        *(uint4*)(T_hi + o) = *(const uint4*)hi;
        *(uint4*)(T_lo + o) = *(const uint4*)lo;
    }
}

// ---------------- K1c: contexts [n,b,c,l] -> ctxT bf16 [n,b,l,c] -------------
__global__ __launch_bounds__(256) void k1c_ctx(const float* __restrict__ ctx,
                                               u16* __restrict__ ctxT) {
    __shared__ float ts[64][33];
    const int tid = threadIdx.x;
    const int lt = blockIdx.x, ct = blockIdx.y, nb = blockIdx.z;
    const long ib = (long)nb * CDF * LSZ;
    {
        const int cl = tid >> 2, l0 = (tid & 3) * 8;
        const float* src = ctx + ib + (long)(ct * 64 + cl) * LSZ + lt * 32 + l0;
        float4 v0 = *(const float4*)src;
        float4 v1 = *(const float4*)(src + 4);
        ts[cl][l0 + 0] = v0.x; ts[cl][l0 + 1] = v0.y;
        ts[cl][l0 + 2] = v0.z; ts[cl][l0 + 3] = v0.w;
        ts[cl][l0 + 4] = v1.x; ts[cl][l0 + 5] = v1.y;
        ts[cl][l0 + 6] = v1.z; ts[cl][l0 + 7] = v1.w;
    }
    __syncthreads();
    {
        const int ll = tid >> 3, c8 = (tid & 7) * 8;
        u16 o8[8];
#pragma unroll
        for (int i = 0; i < 8; ++i) o8[i] = f2bf(ts[c8 + i][ll]);
        const long ob = (long)nb * LSZ * CDF;
        *(uint4*)(ctxT + ob + (long)(lt * 32 + ll) * CDF + ct * 64 + c8) =
            *(const uint4*)o8;
    }
}

// ---------------- K2: sourceT = Wc @ ctx  (per (n,b), hi/lo x hi) ------------
// LDS-staged B tile, counted vmcnt(2), pre-swizzled source; T5 setprio on the
// MFMA cluster (phase-split structure -> wave role diversity, m218b/m224).
__global__ __launch_bounds__(256, 2) void k2_src(const u16* __restrict__ Wc_hi,
                                                 const u16* __restrict__ Wc_lo,
                                                 const u16* __restrict__ ctxT,
                                                 u16* __restrict__ sTT_hi,
                                                 u16* __restrict__ sTT_lo,
                                                 u16* __restrict__ s_dl) {
    __shared__ u16 bounce[128 * 136];
    __shared__ __align__(16) u16 BST[2][4096];   // 2 x 8KB B tiles
    const int tid = threadIdx.x;
    const int L = tid & 63, w = tid >> 6;
    const int wd = w >> 1, wl = w & 1, lr = L & 15, quad = L >> 4;
    const int dbase = blockIdx.x * 128;
    const int nb = blockIdx.y;
    const u16* ctxb = ctxT + (long)nb * LSZ * CDF;

    const f32x4 vz = {0.f, 0.f, 0.f, 0.f};
    f32x4 acc[4][4];
#pragma unroll
    for (int m = 0; m < 4; ++m)
#pragma unroll
        for (int nn = 0; nn < 4; ++nn) acc[m][nn] = vz;

    // prologue: stage kc=0 B tile
    stage_128(BST[0], ctxb, CDF, 0, w, L);

    for (int kc = 0; kc < 16; ++kc) {
        const int cur = kc & 1;
        const int c0 = kc * 32 + quad * 8;
        bf16x8 aH[4], aL[4];
#pragma unroll
        for (int m = 0; m < 4; ++m) {
            const int d = dbase + 64 * wd + 16 * m + lr;
            aH[m] = ldg16(Wc_hi + d * CDF + c0);
            aL[m] = ldg16(Wc_lo + d * CDF + c0);
        }
        asm volatile("" ::: "memory");          // A-loads issue before STAGE (vm order)
        if (kc < 15) {
            stage_128(BST[cur ^ 1], ctxb, CDF, (kc + 1) * 32, w, L);
            vm_wait2();                          // retire prev-stage + A; keep 2 in flight
        } else {
            vm_wait0();                          // last step: drain (once)
        }
        mid_bar();

        bf16x8 bb[4];
#pragma unroll
        for (int nn = 0; nn < 4; ++nn)
            bb[nn] = lds16(BST[cur] + swz_off(64 * wl + 16 * nn + lr, quad));
        prio1();
#pragma unroll
        for (int m = 0; m < 4; ++m)
#pragma unroll
            for (int nn = 0; nn < 4; ++nn) {
                acc[m][nn] = mfma16(aH[m], bb[nn], acc[m][nn]);
                acc[m][nn] = mfma16(aL[m], bb[nn], acc[m][nn]);
            }
        prio0();
        end_bar();                               // reads retired before next overwrite
    }

    // ---- epilogue: 3 LDS-bounce passes for coalesced stores ----
#pragma unroll
    for (int m = 0; m < 4; ++m)
#pragma unroll
        for (int nn = 0; nn < 4; ++nn)
#pragma unroll
            for (int r = 0; r < 4; ++r) {
                const int d = 64 * wd + 16 * m + 4 * quad + r;
                const int l = 64 * wl + 16 * nn + lr;
                bounce[l * 136 + d] = f2bf(acc[m][nn][r]);
            }
    __syncthreads();
    for (int i = tid; i < 2048; i += 256) {
        const int l = i >> 4, g = (i & 15) * 8;
        *(uint4*)(sTT_hi + ((long)nb * LSZ + l) * IDF + dbase + g) =
            *(const uint4*)(bounce + l * 136 + g);
    }
    __syncthreads();
#pragma unroll
    for (int m = 0; m < 4; ++m)
#pragma unroll
        for (int nn = 0; nn < 4; ++nn)
#pragma unroll
            for (int r = 0; r < 4; ++r) {
                const int d = 64 * wd + 16 * m + 4 * quad + r;
                const int l = 64 * wl + 16 * nn + lr;
                float c = acc[m][nn][r];
                u16 h = f2bf(c);
                bounce[l * 136 + d] = f2bf(c - bf2f(h));
            }
    __syncthreads();
    for (int i = tid; i < 2048; i += 256) {
        const int l = i >> 4, g = (i & 15) * 8;
        *(uint4*)(sTT_lo + ((long)nb * LSZ + l) * IDF + dbase + g) =
            *(const uint4*)(bounce + l * 136 + g);
    }
    __syncthreads();
#pragma unroll
    for (int m = 0; m < 4; ++m)
#pragma unroll
        for (int nn = 0; nn < 4; ++nn)
#pragma unroll
            for (int r = 0; r < 4; ++r) {
                const int d = 64 * wd + 16 * m + 4 * quad + r;
                const int l = 64 * wl + 16 * nn + lr;
                bounce[d * 136 + l] = f2bf(acc[m][nn][r]);
            }
    __syncthreads();
    for (int i = tid; i < 2048; i += 256) {
        const int d = i >> 4, g = (i & 15) * 8;
        *(uint4*)(s_dl + ((long)nb * IDF + dbase + d) * LSZ + g) =
            *(const uint4*)(bounce + d * 136 + g);
    }
}

// ---------------- K3: fused scores->softmax->PV->concat-proj->LN -------------
// Round-7 pipeline + (a) T5 setprio around each MFMA cluster, (b) softmax
// bank-conflict fix: thread (tid&3) handles elements (tid&3)+4i (interleaved)
// instead of a 32-aligned chunk -> bank (4row+(tid&3)+4i)%32 = 2-way (free)
// vs 8-way before (bulk of the 7.86M conflict cycles).
__global__ __launch_bounds__(256, 2) void k3_attn(
    const u16* __restrict__ T_hi, const u16* __restrict__ T_lo,
    const u16* __restrict__ sTT_hi, const u16* __restrict__ sTT_lo,
    const u16* __restrict__ s_dl, const u16* __restrict__ Wcat_bf,
    const float* __restrict__ Wb, const float* __restrict__ gam_p,
    const float* __restrict__ bet_p, float* __restrict__ out)
{
    __shared__ __align__(16) u16 ST[2][8192];   // 2 x 16KB staging buffers
    __shared__ float S[64 * 132];      // scores fp32; overlaid later by attn bf16 [64][264]
    __shared__ float redA[256];
    __shared__ float redB[256];
    u16* attnL = (u16*)S;

    const int tid = threadIdx.x;
    const int L = tid & 63, w = tid >> 6;
    const int wq = w >> 1, wh = w & 1, lr = L & 15, quad = L >> 4;
    const int b = blockIdx.x;                    // b fastest -> XCD = b%8 (T1)
    const int bq = b * QSZ + blockIdx.y * 64;

    const f32x4 vz = {0.f, 0.f, 0.f, 0.f};
    f32x4 x_acc[2][8];
#pragma unroll
    for (int m = 0; m < 2; ++m)
#pragma unroll
        for (int nn = 0; nn < 8; ++nn) x_acc[m][nn] = vz;

    // prologue: stage n=0 ph1 kc=0 tile into ST[0]; visibility comes from the
    // first body's vmcnt(4)+barrier (prologue ops are the oldest 4).
    stage_ph1(ST[0], sTT_hi + (long)b * (LSZ * IDF), sTT_lo + (long)b * (LSZ * IDF),
              0, w, L);

    for (int n = 0; n < NCTX; ++n) {
        const int nb = n * BSZ + b;
        const u16* sttH = sTT_hi + (long)nb * (LSZ * IDF);
        const u16* sttL = sTT_lo + (long)nb * (LSZ * IDF);
        const u16* sdl  = s_dl  + (long)nb * (IDF * LSZ);
        const u16* wcat = Wcat_bf + n * IDF;

        // ---- phase 1: S[64q x 128l] = (T_hi+T_lo).(sTT_hi+sTT_lo)^T, drop lo*lo
        f32x4 s_acc[2][4];
#pragma unroll
        for (int m = 0; m < 2; ++m)
#pragma unroll
            for (int nn = 0; nn < 4; ++nn) s_acc[m][nn] = vz;

        for (int kc = 0; kc < 8; ++kc) {
            const int cur = kc & 1;
            const int c0 = kc * 32 + quad * 8;
            bf16x8 aH[2], aL[2];
#pragma unroll
            for (int m = 0; m < 2; ++m) {
                const int ro = (bq + 32 * wq + 16 * m + lr) * IDF + c0;
                aH[m] = ldg16(T_hi + ro);
                aL[m] = ldg16(T_lo + ro);
            }
            asm volatile("" ::: "memory");      // A-loads issue before STAGE (vm order)
            if (kc < 7) stage_ph1(ST[cur ^ 1], sttH, sttL, (kc + 1) * 32, w, L);
            else        stage_256(ST[cur ^ 1], sdl, LSZ, 0, w, L);   // pre-stage ph2 kc0
            vm_wait4();                          // retire prev-stage + A; keep 4 in flight
            mid_bar();

            const u16* Bh = ST[cur];
            const u16* Bl = ST[cur] + 4096;
            bf16x8 bH[4], bL[4];
#pragma unroll
            for (int nn = 0; nn < 4; ++nn) {
                const int off = swz_off(64 * wh + 16 * nn + lr, quad);
                bH[nn] = lds16(Bh + off);
                bL[nn] = lds16(Bl + off);
            }
            prio1();
#pragma unroll
            for (int m = 0; m < 2; ++m)
#pragma unroll
                for (int nn = 0; nn < 4; ++nn) {
                    s_acc[m][nn] = mfma16(aH[m], bH[nn], s_acc[m][nn]);
                    s_acc[m][nn] = mfma16(aH[m], bL[nn], s_acc[m][nn]);
                    s_acc[m][nn] = mfma16(aL[m], bH[nn], s_acc[m][nn]);
                }
            prio0();
            end_bar();                           // reads retired before next overwrite
        }

#pragma unroll
        for (int m = 0; m < 2; ++m)
#pragma unroll
            for (int nn = 0; nn < 4; ++nn)
#pragma unroll
                for (int r = 0; r < 4; ++r)
                    S[(32 * wq + 16 * m + 4 * quad + r) * 132 + 64 * wh + 16 * nn + lr] =
                        s_acc[m][nn][r];
        lg_bar();

        // ---- softmax over l (per row, 4 threads/row, INTERLEAVED stride-4
        // elements for 2-way banks); keep UNNORMALIZED exp in S
        {
            const int row = tid >> 2, sg = tid & 3;
            float* sp = S + row * 132 + sg;
            float mx = sp[0];
#pragma unroll
            for (int i = 1; i < 32; ++i) mx = fmaxf(mx, sp[4 * i]);
            redA[row * 4 + sg] = mx;
            lg_bar();
            const float rm = fmaxf(fmaxf(redA[row * 4], redA[row * 4 + 1]),
                                   fmaxf(redA[row * 4 + 2], redA[row * 4 + 3]));
            float sm = 0.f;
#pragma unroll
            for (int i = 0; i < 32; ++i) {
                float e = __expf(sp[4 * i] - rm);
                sp[4 * i] = e;
                sm += e;
            }
            redB[row * 4 + sg] = sm;
            lg_bar();
        }

        // ---- phase 2: attn[64q x 256d] = E . s_dl^T  (unnormalized)
        f32x4 a_acc[2][8];
#pragma unroll
        for (int m = 0; m < 2; ++m)
#pragma unroll
            for (int nn = 0; nn < 8; ++nn) a_acc[m][nn] = vz;

        for (int kc = 0; kc < 4; ++kc) {
            const int cur = kc & 1;
            if (kc < 3) stage_256(ST[cur ^ 1], sdl, LSZ, (kc + 1) * 32, w, L);
            else        stage_256(ST[cur ^ 1], wcat, NCTX * IDF, 0, w, L); // pre-stage ph3 kc0
            vm_wait4();
            mid_bar();

            const int l0 = kc * 32 + quad * 8;
            bf16x8 af[2];
#pragma unroll
            for (int m = 0; m < 2; ++m)
                af[m] = pack8(S + (32 * wq + 16 * m + lr) * 132 + l0);
            const u16* Bd = ST[cur];
            prio1();
#pragma unroll
            for (int nn = 0; nn < 8; ++nn) {
                const int off = swz_off(128 * wh + 16 * nn + lr, quad);
                bf16x8 bf = lds16(Bd + off);
#pragma unroll
                for (int m = 0; m < 2; ++m)
                    a_acc[m][nn] = mfma16(af[m], bf, a_acc[m][nn]);
            }
            prio0();
            end_bar();
        }

        float invr[2][4];
#pragma unroll
        for (int m = 0; m < 2; ++m)
#pragma unroll
            for (int r = 0; r < 4; ++r) {
                const int row = 32 * wq + 16 * m + 4 * quad + r;
                invr[m][r] = 1.0f / (redB[row * 4] + redB[row * 4 + 1] +
                                     redB[row * 4 + 2] + redB[row * 4 + 3]);
            }
#pragma unroll
        for (int m = 0; m < 2; ++m)
#pragma unroll
            for (int nn = 0; nn < 8; ++nn)
#pragma unroll
                for (int r = 0; r < 4; ++r) {
                    const int row = 32 * wq + 16 * m + 4 * quad + r;
                    const int col = 128 * wh + 16 * nn + lr;
                    attnL[row * 264 + col] = f2bf(a_acc[m][nn][r] * invr[m][r]);
                }
        lg_bar();

        // ---- phase 3: X[64q x 256e] += attn . Wcat_n^T
        for (int kc = 0; kc < 8; ++kc) {
            const int cur = kc & 1;
            if (kc < 7) stage_256(ST[cur ^ 1], wcat, NCTX * IDF, (kc + 1) * 32, w, L);
            else if (n < NCTX - 1) {
                const u16* nH = sTT_hi + (long)((n + 1) * BSZ + b) * (LSZ * IDF);
                const u16* nL = sTT_lo + (long)((n + 1) * BSZ + b) * (LSZ * IDF);
                stage_ph1(ST[cur ^ 1], nH, nL, 0, w, L);   // pre-stage next-n ph1 kc0
            }
            vm_wait4();
            mid_bar();

            const int d0 = kc * 32 + quad * 8;
            bf16x8 af[2];
#pragma unroll
            for (int m = 0; m < 2; ++m) {
                U4V t;
                t.u = *(const uint4*)(attnL + (32 * wq + 16 * m + lr) * 264 + d0);
                af[m] = t.v;
            }
            const u16* Wt = ST[cur];
            prio1();
#pragma unroll
            for (int nn = 0; nn < 8; ++nn) {
                const int off = swz_off(128 * wh + 16 * nn + lr, quad);
                bf16x8 bf = lds16(Wt + off);
#pragma unroll
                for (int m = 0; m < 2; ++m)
                    x_acc[m][nn] = mfma16(af[m], bf, x_acc[m][nn]);
            }
            prio0();
            end_bar();
        }
    }
    vm_wait0();   // drain any residual (once, post-loop)

    // ---- epilogue: bias + relu + residual + LayerNorm(eps=0) ----
    float gv[8], bv[8], wv[8];
    int ec[8];
#pragma unroll
    for (int nn = 0; nn < 8; ++nn) {
        ec[nn] = 128 * wh + 16 * nn + lr;
        wv[nn] = Wb[ec[nn]];
        gv[nn] = gam_p[ec[nn]];
        bv[nn] = bet_p[ec[nn]];
    }
#pragma unroll
    for (int m = 0; m < 2; ++m)
#pragma unroll
        for (int r = 0; r < 4; ++r) {
            const int row = 32 * wq + 16 * m + 4 * quad + r;
            const u16* th = T_hi + (long)(bq + row) * IDF;
            const u16* tl = T_lo + (long)(bq + row) * IDF;
#pragma unroll
            for (int nn = 0; nn < 8; ++nn) {
                float resid = bf2f(th[ec[nn]]) + bf2f(tl[ec[nn]]);   // ~fp32-exact target
                x_acc[m][nn][r] = fmaxf(x_acc[m][nn][r] + wv[nn], 0.f) + resid;
            }
        }
    float s1[2][4], s2[2][4];
#pragma unroll
    for (int m = 0; m < 2; ++m)
#pragma unroll
        for (int r = 0; r < 4; ++r) {
            float a = 0.f, q2 = 0.f;
#pragma unroll
            for (int nn = 0; nn < 8; ++nn) {
                float v = x_acc[m][nn][r];
                a += v;
                q2 += v * v;
            }
            s1[m][r] = a;
            s2[m][r] = q2;
        }
#pragma unroll
    for (int off = 1; off <= 8; off <<= 1)
#pragma unroll
        for (int m = 0; m < 2; ++m)
#pragma unroll
            for (int r = 0; r < 4; ++r) {
                s1[m][r] += __shfl_xor(s1[m][r], off);
                s2[m][r] += __shfl_xor(s2[m][r], off);
            }
    if (lr == 0) {
#pragma unroll
        for (int m = 0; m < 2; ++m)
#pragma unroll
            for (int r = 0; r < 4; ++r) {
                const int row = 32 * wq + 16 * m + 4 * quad + r;
                redA[row * 4 + wh * 2]     = s1[m][r];
                redA[row * 4 + wh * 2 + 1] = s2[m][r];
            }
    }
    __syncthreads();
#pragma unroll
    for (int m = 0; m < 2; ++m)
#pragma unroll
        for (int r = 0; r < 4; ++r) {
            const int row = 32 * wq + 16 * m + 4 * quad + r;
            const float S1 = redA[row * 4] + redA[row * 4 + 2];
            const float S2 = redA[row * 4 + 1] + redA[row * 4 + 3];
            const float mu = S1 * (1.f / 256.f);
            const float rs = rsqrtf(S2 * (1.f / 256.f) - mu * mu);
            float* op = out + (long)(bq + row) * IDF;
#pragma unroll
            for (int nn = 0; nn < 8; ++nn)
                op[ec[nn]] = (x_acc[m][nn][r] - mu) * rs * gv[nn] + bv[nn];
        }
}

// ---------------- launch ----------------
extern "C" void kernel_launch(void* const* d_in, const int* in_sizes, int n_in,
                              void* d_out, int out_size, void* d_ws, size_t ws_size,
                              hipStream_t stream) {
    const float* input    = (const float*)d_in[0];
    const float* contexts = (const float*)d_in[1];
    const float* Wc       = (const float*)d_in[2];
    const float* Wcat     = (const float*)d_in[3];
    const float* Wb       = (const float*)d_in[4];
    const float* gamma    = (const float*)d_in[5];
    const float* beta     = (const float*)d_in[6];
    float* out = (float*)d_out;

    char* ws = (char*)d_ws;
    size_t off = 0;
    u16* Wc_hi   = (u16*)(ws + off); off += (size_t)IDF * CDF * 2;          // 256 KB
    u16* Wc_lo   = (u16*)(ws + off); off += (size_t)IDF * CDF * 2;          // 256 KB
    u16* Wcat_bf = (u16*)(ws + off); off += (size_t)IDF * NCTX * IDF * 2;   // 1.25 MB
    u16* T_hi    = (u16*)(ws + off); off += (size_t)BSZ * QSZ * IDF * 2;    // 16.8 MB
    u16* T_lo    = (u16*)(ws + off); off += (size_t)BSZ * QSZ * IDF * 2;    // 16.8 MB
    u16* ctxT    = (u16*)(ws + off); off += (size_t)NCTX * BSZ * LSZ * CDF * 2; // 41.9 MB
    u16* sTT_hi  = (u16*)(ws + off); off += (size_t)NCTX * BSZ * LSZ * IDF * 2; // 21.0 MB
    u16* sTT_lo  = (u16*)(ws + off); off += (size_t)NCTX * BSZ * LSZ * IDF * 2; // 21.0 MB
    u16* s_dl    = (u16*)(ws + off); off += (size_t)NCTX * BSZ * IDF * LSZ * 2; // 21.0 MB
    (void)in_sizes; (void)n_in; (void)out_size; (void)ws_size;

    k1a_conv<<<3072, 256, 0, stream>>>(Wc, Wcat, Wc_hi, Wc_lo, Wcat_bf);
    k1b_tgt<<<dim3(QSZ / 32, IDF / 64, BSZ), 256, 0, stream>>>(input, T_hi, T_lo);
    k1c_ctx<<<dim3(LSZ / 32, CDF / 64, NCTX * BSZ), 256, 0, stream>>>(contexts, ctxT);
    k2_src<<<dim3(2, NCTX * BSZ), 256, 0, stream>>>(Wc_hi, Wc_lo, ctxT, sTT_hi, sTT_lo, s_dl);
    k3_attn<<<dim3(BSZ, QSZ / 64), 256, 0, stream>>>(T_hi, T_lo, sTT_hi, sTT_lo, s_dl,
                                                     Wcat_bf, Wb, gamma, beta, out);
}

// Round 9
// 510.056 us; speedup vs baseline: 1.0208x; 1.0208x over previous
//
#include <hip/hip_runtime.h>
#include <cstdint>

typedef unsigned short u16;
typedef unsigned int   u32;
typedef __bf16 bf16x8 __attribute__((ext_vector_type(8)));
typedef float  f32x4  __attribute__((ext_vector_type(4)));

#define NCTX 10
#define BSZ  32
#define IDF  256
#define QSZ  1024
#define CDF  512
#define LSZ  128

__device__ __forceinline__ u16 f2bf(float f) {
    u32 u = __float_as_uint(f);
    u += 0x7FFFu + ((u >> 16) & 1u);          // RNE to bf16
    return (u16)(u >> 16);
}
__device__ __forceinline__ float bf2f(u16 h) {
    return __uint_as_float(((u32)h) << 16);
}

union U4V { uint4 u; bf16x8 v; };

__device__ __forceinline__ bf16x8 ldg16(const u16* p) {   // 8 contiguous bf16 (16B)
    U4V t; t.u = *(const uint4*)p; return t.v;
}
__device__ __forceinline__ bf16x8 lds16(const u16* p) {   // 8 bf16 from LDS (ds_read_b128)
    U4V t; t.u = *(const uint4*)p; return t.v;
}
__device__ __forceinline__ bf16x8 pack8(const float* f) { // 8 f32 -> bf16x8 (RNE)
    U4V t;
    t.u.x = (u32)f2bf(f[0]) | ((u32)f2bf(f[1]) << 16);
    t.u.y = (u32)f2bf(f[2]) | ((u32)f2bf(f[3]) << 16);
    t.u.z = (u32)f2bf(f[4]) | ((u32)f2bf(f[5]) << 16);
    t.u.w = (u32)f2bf(f[6]) | ((u32)f2bf(f[7]) << 16);
    return t.v;
}
__device__ __forceinline__ f32x4 mfma16(bf16x8 a, bf16x8 b, f32x4 c) {
    return __builtin_amdgcn_mfma_f32_16x16x32_bf16(a, b, c, 0, 0, 0);
}

// async global->LDS, 16B per lane; LDS dest is wave-uniform base + lane*16
__device__ __forceinline__ void gl_lds16(const u16* g, u16* l) {
    __builtin_amdgcn_global_load_lds(
        (__attribute__((address_space(1))) void*)(g),
        (__attribute__((address_space(3))) void*)(l), 16, 0, 0);
}

// ---- sync primitives (counted-vmcnt pipeline; never drain vm in the k-loop)
__device__ __forceinline__ void vm_wait8() {
    asm volatile("s_waitcnt vmcnt(8)" ::: "memory");
    __builtin_amdgcn_sched_barrier(0);
}
__device__ __forceinline__ void vm_wait4() {
    asm volatile("s_waitcnt vmcnt(4)" ::: "memory");
    __builtin_amdgcn_sched_barrier(0);
}
__device__ __forceinline__ void vm_wait2() {
    asm volatile("s_waitcnt vmcnt(2)" ::: "memory");
    __builtin_amdgcn_sched_barrier(0);
}
__device__ __forceinline__ void vm_wait0() {
    asm volatile("s_waitcnt vmcnt(0)" ::: "memory");
    __builtin_amdgcn_sched_barrier(0);
}
__device__ __forceinline__ void mid_bar()  {
    __builtin_amdgcn_s_barrier();
    asm volatile("" ::: "memory");
}
__device__ __forceinline__ void end_bar()  {
    asm volatile("" ::: "memory");
    __builtin_amdgcn_s_barrier();
    asm volatile("" ::: "memory");
}
__device__ __forceinline__ void lg_bar()   {   // LDS-visibility barrier, no vm drain
    asm volatile("s_waitcnt lgkmcnt(0)" ::: "memory");
    __builtin_amdgcn_sched_barrier(0);
    __builtin_amdgcn_s_barrier();
    asm volatile("" ::: "memory");
}

// ---- staging helpers ----
// Tiles row-major [rows][32] bf16 (64B rows), staged in 1KB chunks of 16 rows.
// Bank swizzle (T2 via pre-swizzled SOURCE, m173): LDS slot (L&3) of row
// rr=L>>2 holds global colgroup ((L&3)+(rr>>1))&3. Reader inverts. (8-way
// conflict without it: 21M cycles round 4 -> 7.9M round 6.)
__device__ __forceinline__ int swz_cg(int L) {
    return (((L & 3) + ((L >> 3) & 3)) & 3) * 8;     // element offset of source colgroup
}
__device__ __forceinline__ int swz_off(int row, int quad) {
    return row * 32 + ((quad - (row >> 1)) & 3) * 8; // element offset for reader
}

// ph1 tile: Bh[128][32] at buf[0..4095], Bl[128][32] at buf[4096..8191]
__device__ __forceinline__ void stage_ph1(u16* buf, const u16* sttH, const u16* sttL,
                                          int c0, int w, int L) {
    const int rr = L >> 2, cg = swz_cg(L);
#pragma unroll
    for (int j = 0; j < 4; ++j) {
        const int c = 4 * w + j;                 // 0..15, wave-uniform
        const int hi = (c < 8);
        const int ch = hi ? c : c - 8;
        const u16* src = (hi ? sttH : sttL) + (long)(ch * 16 + rr) * IDF + c0 + cg;
        gl_lds16(src, buf + (hi ? 0 : 4096) + ch * 512);
    }
}

// 256-row tile [256][32] filling a 16KB buffer
__device__ __forceinline__ void stage_256(u16* buf, const u16* gbase, int stride,
                                          int c0, int w, int L) {
    const int rr = L >> 2, cg = swz_cg(L);
#pragma unroll
    for (int j = 0; j < 4; ++j) {
        const int c = 4 * w + j;                 // 0..15
        const u16* src = gbase + (long)(c * 16 + rr) * stride + c0 + cg;
        gl_lds16(src, buf + c * 512);
    }
}

// 128-row tile [128][32] filling an 8KB buffer (k2's B tile): 2 chunks/wave
__device__ __forceinline__ void stage_128(u16* buf, const u16* gbase, int stride,
                                          int c0, int w, int L) {
    const int rr = L >> 2, cg = swz_cg(L);
#pragma unroll
    for (int j = 0; j < 2; ++j) {
        const int c = 2 * w + j;                 // 0..7
        const u16* src = gbase + (long)(c * 16 + rr) * stride + c0 + cg;
        gl_lds16(src, buf + c * 512);
    }
}

// ---------------- K1a: weights -> bf16 (Wc hi/lo, Wcat plain) ----------------
__global__ __launch_bounds__(256) void k1a_conv(const float* __restrict__ Wc,
                                                const float* __restrict__ Wcat,
                                                u16* __restrict__ Wc_hi,
                                                u16* __restrict__ Wc_lo,
                                                u16* __restrict__ Wcat_bf) {
    int i = blockIdx.x * 256 + threadIdx.x;
    if (i < IDF * CDF) {
        float f = Wc[i];
        u16 h = f2bf(f);
        Wc_hi[i] = h;
        Wc_lo[i] = f2bf(f - bf2f(h));
    } else {
        int j = i - IDF * CDF;
        Wcat_bf[j] = f2bf(Wcat[j]);
    }
}

// ---------------- K1b: input [B,idf,Q] -> T_hi/T_lo [B,Q,idf] ----------------
__global__ __launch_bounds__(256) void k1b_tgt(const float* __restrict__ input,
                                               u16* __restrict__ T_hi,
                                               u16* __restrict__ T_lo) {
    __shared__ float ts[64][33];
    const int tid = threadIdx.x;
    const int qt = blockIdx.x, dt = blockIdx.y, b = blockIdx.z;
    {
        const int dl = tid >> 2, q0 = (tid & 3) * 8;
        const float* src = input + ((long)(b * IDF + dt * 64 + dl)) * QSZ + qt * 32 + q0;
        float4 v0 = *(const float4*)src;
        float4 v1 = *(const float4*)(src + 4);
        ts[dl][q0 + 0] = v0.x; ts[dl][q0 + 1] = v0.y;
        ts[dl][q0 + 2] = v0.z; ts[dl][q0 + 3] = v0.w;
        ts[dl][q0 + 4] = v1.x; ts[dl][q0 + 5] = v1.y;
        ts[dl][q0 + 6] = v1.z; ts[dl][q0 + 7] = v1.w;
    }
    __syncthreads();
    {
        const int ql = tid >> 3, d8 = (tid & 7) * 8;
        u16 hi[8], lo[8];
#pragma unroll
        for (int i = 0; i < 8; ++i) {
            float f = ts[d8 + i][ql];
            hi[i] = f2bf(f);
            lo[i] = f2bf(f - bf2f(hi[i]));
        }
        const long o = ((long)(b * QSZ + qt * 32 + ql)) * IDF + dt * 64 + d8;
        *(uint4*)(T_hi + o) = *(const uint4*)hi;
        *(uint4*)(T_lo + o) = *(const uint4*)lo;
    }
}

// ---------------- K1c: contexts [n,b,c,l] -> ctxT bf16 [n,b,l,c] -------------
__global__ __launch_bounds__(256) void k1c_ctx(const float* __restrict__ ctx,
                                               u16* __restrict__ ctxT) {
    __shared__ float ts[64][33];
    const int tid = threadIdx.x;
    const int lt = blockIdx.x, ct = blockIdx.y, nb = blockIdx.z;
    const long ib = (long)nb * CDF * LSZ;
    {
        const int cl = tid >> 2, l0 = (tid & 3) * 8;
        const float* src = ctx + ib + (long)(ct * 64 + cl) * LSZ + lt * 32 + l0;
        float4 v0 = *(const float4*)src;
        float4 v1 = *(const float4*)(src + 4);
        ts[cl][l0 + 0] = v0.x; ts[cl][l0 + 1] = v0.y;
        ts[cl][l0 + 2] = v0.z; ts[cl][l0 + 3] = v0.w;
        ts[cl][l0 + 4] = v1.x; ts[cl][l0 + 5] = v1.y;
        ts[cl][l0 + 6] = v1.z; ts[cl][l0 + 7] = v1.w;
    }
    __syncthreads();
    {
        const int ll = tid >> 3, c8 = (tid & 7) * 8;
        u16 o8[8];
#pragma unroll
        for (int i = 0; i < 8; ++i) o8[i] = f2bf(ts[c8 + i][ll]);
        const long ob = (long)nb * LSZ * CDF;
        *(uint4*)(ctxT + ob + (long)(lt * 32 + ll) * CDF + ct * 64 + c8) =
            *(const uint4*)o8;
    }
}

// ---------------- K2: sourceT = Wc @ ctx  (per (n,b), hi/lo x hi) ------------
// LDS-staged B tile, counted vmcnt(2), pre-swizzled source (round-7 verified;
// round-8 setprio reverted: lockstep structure -> m190 negative).
__global__ __launch_bounds__(256, 2) void k2_src(const u16* __restrict__ Wc_hi,
                                                 const u16* __restrict__ Wc_lo,
                                                 const u16* __restrict__ ctxT,
                                                 u16* __restrict__ sTT_hi,
                                                 u16* __restrict__ sTT_lo,
                                                 u16* __restrict__ s_dl) {
    __shared__ u16 bounce[128 * 136];
    __shared__ __align__(16) u16 BST[2][4096];   // 2 x 8KB B tiles
    const int tid = threadIdx.x;
    const int L = tid & 63, w = tid >> 6;
    const int wd = w >> 1, wl = w & 1, lr = L & 15, quad = L >> 4;
    const int dbase = blockIdx.x * 128;
    const int nb = blockIdx.y;
    const u16* ctxb = ctxT + (long)nb * LSZ * CDF;

    const f32x4 vz = {0.f, 0.f, 0.f, 0.f};
    f32x4 acc[4][4];
#pragma unroll
    for (int m = 0; m < 4; ++m)
#pragma unroll
        for (int nn = 0; nn < 4; ++nn) acc[m][nn] = vz;

    // prologue: stage kc=0 B tile
    stage_128(BST[0], ctxb, CDF, 0, w, L);

    for (int kc = 0; kc < 16; ++kc) {
        const int cur = kc & 1;
        const int c0 = kc * 32 + quad * 8;
        bf16x8 aH[4], aL[4];
#pragma unroll
        for (int m = 0; m < 4; ++m) {
            const int d = dbase + 64 * wd + 16 * m + lr;
            aH[m] = ldg16(Wc_hi + d * CDF + c0);
            aL[m] = ldg16(Wc_lo + d * CDF + c0);
        }
        asm volatile("" ::: "memory");          // A-loads issue before STAGE (vm order)
        if (kc < 15) {
            stage_128(BST[cur ^ 1], ctxb, CDF, (kc + 1) * 32, w, L);
            vm_wait2();                          // retire prev-stage + A; keep 2 in flight
        } else {
            vm_wait0();                          // last step: drain (once)
        }
        mid_bar();

        bf16x8 bb[4];
#pragma unroll
        for (int nn = 0; nn < 4; ++nn)
            bb[nn] = lds16(BST[cur] + swz_off(64 * wl + 16 * nn + lr, quad));
#pragma unroll
        for (int m = 0; m < 4; ++m)
#pragma unroll
            for (int nn = 0; nn < 4; ++nn) {
                acc[m][nn] = mfma16(aH[m], bb[nn], acc[m][nn]);
                acc[m][nn] = mfma16(aL[m], bb[nn], acc[m][nn]);
            }
        end_bar();                               // reads retired before next overwrite
    }

    // ---- epilogue: 3 LDS-bounce passes for coalesced stores ----
#pragma unroll
    for (int m = 0; m < 4; ++m)
#pragma unroll
        for (int nn = 0; nn < 4; ++nn)
#pragma unroll
            for (int r = 0; r < 4; ++r) {
                const int d = 64 * wd + 16 * m + 4 * quad + r;
                const int l = 64 * wl + 16 * nn + lr;
                bounce[l * 136 + d] = f2bf(acc[m][nn][r]);
            }
    __syncthreads();
    for (int i = tid; i < 2048; i += 256) {
        const int l = i >> 4, g = (i & 15) * 8;
        *(uint4*)(sTT_hi + ((long)nb * LSZ + l) * IDF + dbase + g) =
            *(const uint4*)(bounce + l * 136 + g);
    }
    __syncthreads();
#pragma unroll
    for (int m = 0; m < 4; ++m)
#pragma unroll
        for (int nn = 0; nn < 4; ++nn)
#pragma unroll
            for (int r = 0; r < 4; ++r) {
                const int d = 64 * wd + 16 * m + 4 * quad + r;
                const int l = 64 * wl + 16 * nn + lr;
                float c = acc[m][nn][r];
                u16 h = f2bf(c);
                bounce[l * 136 + d] = f2bf(c - bf2f(h));
            }
    __syncthreads();
    for (int i = tid; i < 2048; i += 256) {
        const int l = i >> 4, g = (i & 15) * 8;
        *(uint4*)(sTT_lo + ((long)nb * LSZ + l) * IDF + dbase + g) =
            *(const uint4*)(bounce + l * 136 + g);
    }
    __syncthreads();
#pragma unroll
    for (int m = 0; m < 4; ++m)
#pragma unroll
        for (int nn = 0; nn < 4; ++nn)
#pragma unroll
            for (int r = 0; r < 4; ++r) {
                const int d = 64 * wd + 16 * m + 4 * quad + r;
                const int l = 64 * wl + 16 * nn + lr;
                bounce[d * 136 + l] = f2bf(acc[m][nn][r]);
            }
    __syncthreads();
    for (int i = tid; i < 2048; i += 256) {
        const int d = i >> 4, g = (i & 15) * 8;
        *(uint4*)(s_dl + ((long)nb * IDF + dbase + d) * LSZ + g) =
            *(const uint4*)(bounce + d * 136 + g);
    }
}

// ---------------- K3: fused scores->softmax->PV->concat-proj->LN -------------
// Round-7 pipeline (verified 283us) + ph1 A-register double-buffer prefetch:
// A(kc+1) issued WITH stage(kc+1), waited via vmcnt(8) -> A gets a full
// kc-step of flight instead of ~20 instructions (the ~200-400cy L2 stall per
// ph1 step was the remaining exposed latency). A(0) for next n issued at ph3
// kc7 (A is n-invariant). Round-8 setprio + softmax-interleave reverted
// (bundled change regressed 283->302; conflicts fell but weren't on the
// critical path).
// vmcnt ledger: ph1 kc<7: out=[A(kc),st(kc),A(kc+1),st(kc+1)]=16 -> wait8.
// ph1 kc7: out=[A(7),st(7),st_ph2]=12 -> wait4. ph2: wait4 (unchanged).
// ph3 kc<7: wait4. ph3 kc7 n<9: out=[st(7),A(0),st_ph1]=12 -> wait8.
// ph3 kc7 n=9: out=[st(7)]=4 -> wait0 (fixes round-7's latent hole where
// wait4 didn't actually cover st(7)).
__global__ __launch_bounds__(256, 2) void k3_attn(
    const u16* __restrict__ T_hi, const u16* __restrict__ T_lo,
    const u16* __restrict__ sTT_hi, const u16* __restrict__ sTT_lo,
    const u16* __restrict__ s_dl, const u16* __restrict__ Wcat_bf,
    const float* __restrict__ Wb, const float* __restrict__ gam_p,
    const float* __restrict__ bet_p, float* __restrict__ out)
{
    __shared__ __align__(16) u16 ST[2][8192];   // 2 x 16KB staging buffers
    __shared__ float S[64 * 132];      // scores fp32; overlaid later by attn bf16 [64][264]
    __shared__ float redA[256];
    __shared__ float redB[256];
    u16* attnL = (u16*)S;

    const int tid = threadIdx.x;
    const int L = tid & 63, w = tid >> 6;
    const int wq = w >> 1, wh = w & 1, lr = L & 15, quad = L >> 4;
    const int b = blockIdx.x;                    // b fastest -> XCD = b%8 (T1)
    const int bq = b * QSZ + blockIdx.y * 64;

    const f32x4 vz = {0.f, 0.f, 0.f, 0.f};
    f32x4 x_acc[2][8];
#pragma unroll
    for (int m = 0; m < 2; ++m)
#pragma unroll
        for (int nn = 0; nn < 8; ++nn) x_acc[m][nn] = vz;

    // A-fragment double buffer (ph1): slot kc&1 holds A(kc). +32 VGPR.
    bf16x8 aHr[2][2], aLr[2][2];

    // prologue: issue A(0) then stage n=0 ph1 kc=0 tile into ST[0].
#pragma unroll
    for (int m = 0; m < 2; ++m) {
        const int ro = (bq + 32 * wq + 16 * m + lr) * IDF + quad * 8;
        aHr[0][m] = ldg16(T_hi + ro);
        aLr[0][m] = ldg16(T_lo + ro);
    }
    asm volatile("" ::: "memory");
    stage_ph1(ST[0], sTT_hi + (long)b * (LSZ * IDF), sTT_lo + (long)b * (LSZ * IDF),
              0, w, L);

    for (int n = 0; n < NCTX; ++n) {
        const int nb = n * BSZ + b;
        const u16* sttH = sTT_hi + (long)nb * (LSZ * IDF);
        const u16* sttL = sTT_lo + (long)nb * (LSZ * IDF);
        const u16* sdl  = s_dl  + (long)nb * (IDF * LSZ);
        const u16* wcat = Wcat_bf + n * IDF;

        // ---- phase 1: S[64q x 128l] = (T_hi+T_lo).(sTT_hi+sTT_lo)^T, drop lo*lo
        f32x4 s_acc[2][4];
#pragma unroll
        for (int m = 0; m < 2; ++m)
#pragma unroll
            for (int nn = 0; nn < 4; ++nn) s_acc[m][nn] = vz;

#pragma unroll
        for (int kc = 0; kc < 8; ++kc) {
            const int cur = kc & 1;
            if (kc < 7) {
                const int c1 = (kc + 1) * 32 + quad * 8;
#pragma unroll
                for (int m = 0; m < 2; ++m) {
                    const int ro = (bq + 32 * wq + 16 * m + lr) * IDF + c1;
                    aHr[(kc + 1) & 1][m] = ldg16(T_hi + ro);
                    aLr[(kc + 1) & 1][m] = ldg16(T_lo + ro);
                }
                asm volatile("" ::: "memory");  // A-issue before stage (vm order)
                stage_ph1(ST[cur ^ 1], sttH, sttL, (kc + 1) * 32, w, L);
                vm_wait8();                      // retire A(kc)+stage(kc)
            } else {
                stage_256(ST[cur ^ 1], sdl, LSZ, 0, w, L);   // pre-stage ph2 kc0
                vm_wait4();                      // retire A(7)+stage(7)
            }
            mid_bar();

            const u16* Bh = ST[cur];
            const u16* Bl = ST[cur] + 4096;
            bf16x8 bH[4], bL[4];
#pragma unroll
            for (int nn = 0; nn < 4; ++nn) {
                const int off = swz_off(64 * wh + 16 * nn + lr, quad);
                bH[nn] = lds16(Bh + off);
                bL[nn] = lds16(Bl + off);
            }
#pragma unroll
            for (int m = 0; m < 2; ++m)
#pragma unroll
                for (int nn = 0; nn < 4; ++nn) {
                    s_acc[m][nn] = mfma16(aHr[cur][m], bH[nn], s_acc[m][nn]);
                    s_acc[m][nn] = mfma16(aHr[cur][m], bL[nn], s_acc[m][nn]);
                    s_acc[m][nn] = mfma16(aLr[cur][m], bH[nn], s_acc[m][nn]);
                }
            end_bar();                           // reads retired before next overwrite
        }

#pragma unroll
        for (int m = 0; m < 2; ++m)
#pragma unroll
            for (int nn = 0; nn < 4; ++nn)
#pragma unroll
                for (int r = 0; r < 4; ++r)
                    S[(32 * wq + 16 * m + 4 * quad + r) * 132 + 64 * wh + 16 * nn + lr] =
                        s_acc[m][nn][r];
        lg_bar();

        // ---- softmax over l (per row, 4 threads/row); keep UNNORMALIZED exp in S
        {
            const int row = tid >> 2, sg = (tid & 3) * 32;
            float* sp = S + row * 132 + sg;
            float mx = sp[0];
#pragma unroll
            for (int i = 1; i < 32; ++i) mx = fmaxf(mx, sp[i]);
            redA[row * 4 + (tid & 3)] = mx;
            lg_bar();
            const float rm = fmaxf(fmaxf(redA[row * 4], redA[row * 4 + 1]),
                                   fmaxf(redA[row * 4 + 2], redA[row * 4 + 3]));
            float sm = 0.f;
#pragma unroll
            for (int i = 0; i < 32; ++i) {
                float e = __expf(sp[i] - rm);
                sp[i] = e;
                sm += e;
            }
            redB[row * 4 + (tid & 3)] = sm;
            lg_bar();
        }

        // ---- phase 2: attn[64q x 256d] = E . s_dl^T  (unnormalized)
        f32x4 a_acc[2][8];
#pragma unroll
        for (int m = 0; m < 2; ++m)
#pragma unroll
            for (int nn = 0; nn < 8; ++nn) a_acc[m][nn] = vz;

        for (int kc = 0; kc < 4; ++kc) {
            const int cur = kc & 1;
            if (kc < 3) stage_256(ST[cur ^ 1], sdl, LSZ, (kc + 1) * 32, w, L);
            else        stage_256(ST[cur ^ 1], wcat, NCTX * IDF, 0, w, L); // pre-stage ph3 kc0
            vm_wait4();
            mid_bar();

            const int l0 = kc * 32 + quad * 8;
            bf16x8 af[2];
#pragma unroll
            for (int m = 0; m < 2; ++m)
                af[m] = pack8(S + (32 * wq + 16 * m + lr) * 132 + l0);
            const u16* Bd = ST[cur];
#pragma unroll
            for (int nn = 0; nn < 8; ++nn) {
                const int off = swz_off(128 * wh + 16 * nn + lr, quad);
                bf16x8 bf = lds16(Bd + off);
#pragma unroll
                for (int m = 0; m < 2; ++m)
                    a_acc[m][nn] = mfma16(af[m], bf, a_acc[m][nn]);
            }
            end_bar();
        }

        float invr[2][4];
#pragma unroll
        for (int m = 0; m < 2; ++m)
#pragma unroll
            for (int r = 0; r < 4; ++r) {
                const int row = 32 * wq + 16 * m + 4 * quad + r;
                invr[m][r] = 1.0f / (redB[row * 4] + redB[row * 4 + 1] +
                                     redB[row * 4 + 2] + redB[row * 4 + 3]);
            }
#pragma unroll
        for (int m = 0; m < 2; ++m)
#pragma unroll
            for (int nn = 0; nn < 8; ++nn)
#pragma unroll
                for (int r = 0; r < 4; ++r) {
                    const int row = 32 * wq + 16 * m + 4 * quad + r;
                    const int col = 128 * wh + 16 * nn + lr;
                    attnL[row * 264 + col] = f2bf(a_acc[m][nn][r] * invr[m][r]);
                }
        lg_bar();

        // ---- phase 3: X[64q x 256e] += attn . Wcat_n^T
        for (int kc = 0; kc < 8; ++kc) {
            const int cur = kc & 1;
            if (kc < 7) {
                stage_256(ST[cur ^ 1], wcat, NCTX * IDF, (kc + 1) * 32, w, L);
                vm_wait4();
            } else if (n < NCTX - 1) {
                // issue next-n A(0) then next-n ph1 kc0 stage
#pragma unroll
                for (int m = 0; m < 2; ++m) {
                    const int ro = (bq + 32 * wq + 16 * m + lr) * IDF + quad * 8;
                    aHr[0][m] = ldg16(T_hi + ro);
                    aLr[0][m] = ldg16(T_lo + ro);
                }
                asm volatile("" ::: "memory");
                const u16* nH = sTT_hi + (long)((n + 1) * BSZ + b) * (LSZ * IDF);
                const u16* nL = sTT_lo + (long)((n + 1) * BSZ + b) * (LSZ * IDF);
                stage_ph1(ST[cur ^ 1], nH, nL, 0, w, L);
                vm_wait8();                      // retire stage(7); keep A(0)+stage_ph1
            } else {
                vm_wait0();                      // true last step: drain stage(7)
            }
            mid_bar();

            const int d0 = kc * 32 + quad * 8;
            bf16x8 af[2];
#pragma unroll
            for (int m = 0; m < 2; ++m) {
                U4V t;
                t.u = *(const uint4*)(attnL + (32 * wq + 16 * m + lr) * 264 + d0);
                af[m] = t.v;
            }
            const u16* Wt = ST[cur];
#pragma unroll
            for (int nn = 0; nn < 8; ++nn) {
                const int off = swz_off(128 * wh + 16 * nn + lr, quad);
                bf16x8 bf = lds16(Wt + off);
#pragma unroll
                for (int m = 0; m < 2; ++m)
                    x_acc[m][nn] = mfma16(af[m], bf, x_acc[m][nn]);
            }
            end_bar();
        }
    }
    vm_wait0();   // safety drain (no-op in steady exit)

    // ---- epilogue: bias + relu + residual + LayerNorm(eps=0) ----
    float gv[8], bv[8], wv[8];
    int ec[8];
#pragma unroll
    for (int nn = 0; nn < 8; ++nn) {
        ec[nn] = 128 * wh + 16 * nn + lr;
        wv[nn] = Wb[ec[nn]];
        gv[nn] = gam_p[ec[nn]];
        bv[nn] = bet_p[ec[nn]];
    }
#pragma unroll
    for (int m = 0; m < 2; ++m)
#pragma unroll
        for (int r = 0; r < 4; ++r) {
            const int row = 32 * wq + 16 * m + 4 * quad + r;
            const u16* th = T_hi + (long)(bq + row) * IDF;
            const u16* tl = T_lo + (long)(bq + row) * IDF;
#pragma unroll
            for (int nn = 0; nn < 8; ++nn) {
                float resid = bf2f(th[ec[nn]]) + bf2f(tl[ec[nn]]);   // ~fp32-exact target
                x_acc[m][nn][r] = fmaxf(x_acc[m][nn][r] + wv[nn], 0.f) + resid;
            }
        }
    float s1[2][4], s2[2][4];
#pragma unroll
    for (int m = 0; m < 2; ++m)
#pragma unroll
        for (int r = 0; r < 4; ++r) {
            float a = 0.f, q2 = 0.f;
#pragma unroll
            for (int nn = 0; nn < 8; ++nn) {
                float v = x_acc[m][nn][r];
                a += v;
                q2 += v * v;
            }
            s1[m][r] = a;
            s2[m][r] = q2;
        }
#pragma unroll
    for (int off = 1; off <= 8; off <<= 1)
#pragma unroll
        for (int m = 0; m < 2; ++m)
#pragma unroll
            for (int r = 0; r < 4; ++r) {
                s1[m][r] += __shfl_xor(s1[m][r], off);
                s2[m][r] += __shfl_xor(s2[m][r], off);
            }
    if (lr == 0) {
#pragma unroll
        for (int m = 0; m < 2; ++m)
#pragma unroll
            for (int r = 0; r < 4; ++r) {
                const int row = 32 * wq + 16 * m + 4 * quad + r;
                redA[row * 4 + wh * 2]     = s1[m][r];
                redA[row * 4 + wh * 2 + 1] = s2[m][r];
            }
    }
    __syncthreads();
#pragma unroll
    for (int m = 0; m < 2; ++m)
#pragma unroll
        for (int r = 0; r < 4; ++r) {
            const int row = 32 * wq + 16 * m + 4 * quad + r;
            const float S1 = redA[row * 4] + redA[row * 4 + 2];
            const float S2 = redA[row * 4 + 1] + redA[row * 4 + 3];
            const float mu = S1 * (1.f / 256.f);
            const float rs = rsqrtf(S2 * (1.f / 256.f) - mu * mu);
            float* op = out + (long)(bq + row) * IDF;
#pragma unroll
            for (int nn = 0; nn < 8; ++nn)
                op[ec[nn]] = (x_acc[m][nn][r] - mu) * rs * gv[nn] + bv[nn];
        }
}

// ---------------- launch ----------------
extern "C" void kernel_launch(void* const* d_in, const int* in_sizes, int n_in,
                              void* d_out, int out_size, void* d_ws, size_t ws_size,
                              hipStream_t stream) {
    const float* input    = (const float*)d_in[0];
    const float* contexts = (const float*)d_in[1];
    const float* Wc       = (const float*)d_in[2];
    const float* Wcat     = (const float*)d_in[3];
    const float* Wb       = (const float*)d_in[4];
    const float* gamma    = (const float*)d_in[5];
    const float* beta     = (const float*)d_in[6];
    float* out = (float*)d_out;

    char* ws = (char*)d_ws;
    size_t off = 0;
    u16* Wc_hi   = (u16*)(ws + off); off += (size_t)IDF * CDF * 2;          // 256 KB
    u16* Wc_lo   = (u16*)(ws + off); off += (size_t)IDF * CDF * 2;          // 256 KB
    u16* Wcat_bf = (u16*)(ws + off); off += (size_t)IDF * NCTX * IDF * 2;   // 1.25 MB
    u16* T_hi    = (u16*)(ws + off); off += (size_t)BSZ * QSZ * IDF * 2;    // 16.8 MB
    u16* T_lo    = (u16*)(ws + off); off += (size_t)BSZ * QSZ * IDF * 2;    // 16.8 MB
    u16* ctxT    = (u16*)(ws + off); off += (size_t)NCTX * BSZ * LSZ * CDF * 2; // 41.9 MB
    u16* sTT_hi  = (u16*)(ws + off); off += (size_t)NCTX * BSZ * LSZ * IDF * 2; // 21.0 MB
    u16* sTT_lo  = (u16*)(ws + off); off += (size_t)NCTX * BSZ * LSZ * IDF * 2; // 21.0 MB
    u16* s_dl    = (u16*)(ws + off); off += (size_t)NCTX * BSZ * IDF * LSZ * 2; // 21.0 MB
    (void)in_sizes; (void)n_in; (void)out_size; (void)ws_size;

    k1a_conv<<<3072, 256, 0, stream>>>(Wc, Wcat, Wc_hi, Wc_lo, Wcat_bf);
    k1b_tgt<<<dim3(QSZ / 32, IDF / 64, BSZ), 256, 0, stream>>>(input, T_hi, T_lo);
    k1c_ctx<<<dim3(LSZ / 32, CDF / 64, NCTX * BSZ), 256, 0, stream>>>(contexts, ctxT);
    k2_src<<<dim3(2, NCTX * BSZ), 256, 0, stream>>>(Wc_hi, Wc_lo, ctxT, sTT_hi, sTT_lo, s_dl);
    k3_attn<<<dim3(BSZ, QSZ / 64), 256, 0, stream>>>(T_hi, T_lo, sTT_hi, sTT_lo, s_dl,
                                                     Wcat_bf, Wb, gamma, beta, out);
}

// Round 10
// 504.805 us; speedup vs baseline: 1.0315x; 1.0104x over previous
//
#include <hip/hip_runtime.h>
#include <cstdint>

typedef unsigned short u16;
typedef unsigned int   u32;
typedef __bf16 bf16x8 __attribute__((ext_vector_type(8)));
typedef float  f32x4  __attribute__((ext_vector_type(4)));

#define NCTX 10
#define BSZ  32
#define IDF  256
#define QSZ  1024
#define CDF  512
#define LSZ  128

__device__ __forceinline__ u16 f2bf(float f) {
    u32 u = __float_as_uint(f);
    u += 0x7FFFu + ((u >> 16) & 1u);          // RNE to bf16
    return (u16)(u >> 16);
}
__device__ __forceinline__ float bf2f(u16 h) {
    return __uint_as_float(((u32)h) << 16);
}

union U4V { uint4 u; bf16x8 v; };

__device__ __forceinline__ bf16x8 ldg16(const u16* p) {   // 8 contiguous bf16 (16B)
    U4V t; t.u = *(const uint4*)p; return t.v;
}
__device__ __forceinline__ bf16x8 lds16(const u16* p) {   // 8 bf16 from LDS (ds_read_b128)
    U4V t; t.u = *(const uint4*)p; return t.v;
}
__device__ __forceinline__ bf16x8 pack8(const float* f) { // 8 f32 -> bf16x8 (RNE)
    U4V t;
    t.u.x = (u32)f2bf(f[0]) | ((u32)f2bf(f[1]) << 16);
    t.u.y = (u32)f2bf(f[2]) | ((u32)f2bf(f[3]) << 16);
    t.u.z = (u32)f2bf(f[4]) | ((u32)f2bf(f[5]) << 16);
    t.u.w = (u32)f2bf(f[6]) | ((u32)f2bf(f[7]) << 16);
    return t.v;
}
__device__ __forceinline__ f32x4 mfma16(bf16x8 a, bf16x8 b, f32x4 c) {
    return __builtin_amdgcn_mfma_f32_16x16x32_bf16(a, b, c, 0, 0, 0);
}

// async global->LDS, 16B per lane; LDS dest is wave-uniform base + lane*16
__device__ __forceinline__ void gl_lds16(const u16* g, u16* l) {
    __builtin_amdgcn_global_load_lds(
        (__attribute__((address_space(1))) void*)(g),
        (__attribute__((address_space(3))) void*)(l), 16, 0, 0);
}

// ---- sync primitives (counted-vmcnt pipeline; never drain vm in the k-loop)
__device__ __forceinline__ void vm_wait8() {
    asm volatile("s_waitcnt vmcnt(8)" ::: "memory");
    __builtin_amdgcn_sched_barrier(0);
}
__device__ __forceinline__ void vm_wait4() {
    asm volatile("s_waitcnt vmcnt(4)" ::: "memory");
    __builtin_amdgcn_sched_barrier(0);
}
__device__ __forceinline__ void vm_wait2() {
    asm volatile("s_waitcnt vmcnt(2)" ::: "memory");
    __builtin_amdgcn_sched_barrier(0);
}
__device__ __forceinline__ void vm_wait0() {
    asm volatile("s_waitcnt vmcnt(0)" ::: "memory");
    __builtin_amdgcn_sched_barrier(0);
}
__device__ __forceinline__ void mid_bar()  {
    __builtin_amdgcn_s_barrier();
    asm volatile("" ::: "memory");
}
__device__ __forceinline__ void end_bar()  {
    asm volatile("" ::: "memory");
    __builtin_amdgcn_s_barrier();
    asm volatile("" ::: "memory");
}
__device__ __forceinline__ void lg_bar()   {   // LDS-visibility barrier, no vm drain
    asm volatile("s_waitcnt lgkmcnt(0)" ::: "memory");
    __builtin_amdgcn_sched_barrier(0);
    __builtin_amdgcn_s_barrier();
    asm volatile("" ::: "memory");
}

// ---- staging helpers ----
// Tiles row-major [rows][32] bf16 (64B rows), staged in 1KB chunks of 16 rows.
// Bank swizzle (T2 via pre-swizzled SOURCE, m173): LDS slot (L&3) of row
// rr=L>>2 holds global colgroup ((L&3)+(rr>>1))&3. Reader inverts. (8-way
// conflict without it: 21M cycles round 4 -> 7.9M round 6.)
__device__ __forceinline__ int swz_cg(int L) {
    return (((L & 3) + ((L >> 3) & 3)) & 3) * 8;     // element offset of source colgroup
}
__device__ __forceinline__ int swz_off(int row, int quad) {
    return row * 32 + ((quad - (row >> 1)) & 3) * 8; // element offset for reader
}

// ph1 tile: Bh[128][32] at buf[0..4095], Bl[128][32] at buf[4096..8191]
__device__ __forceinline__ void stage_ph1(u16* buf, const u16* sttH, const u16* sttL,
                                          int c0, int w, int L) {
    const int rr = L >> 2, cg = swz_cg(L);
#pragma unroll
    for (int j = 0; j < 4; ++j) {
        const int c = 4 * w + j;                 // 0..15, wave-uniform
        const int hi = (c < 8);
        const int ch = hi ? c : c - 8;
        const u16* src = (hi ? sttH : sttL) + (long)(ch * 16 + rr) * IDF + c0 + cg;
        gl_lds16(src, buf + (hi ? 0 : 4096) + ch * 512);
    }
}

// 256-row tile [256][32] filling a 16KB buffer
__device__ __forceinline__ void stage_256(u16* buf, const u16* gbase, int stride,
                                          int c0, int w, int L) {
    const int rr = L >> 2, cg = swz_cg(L);
#pragma unroll
    for (int j = 0; j < 4; ++j) {
        const int c = 4 * w + j;                 // 0..15
        const u16* src = gbase + (long)(c * 16 + rr) * stride + c0 + cg;
        gl_lds16(src, buf + c * 512);
    }
}

// 128-row tile [128][32] filling an 8KB buffer (k2's B tile): 2 chunks/wave
__device__ __forceinline__ void stage_128(u16* buf, const u16* gbase, int stride,
                                          int c0, int w, int L) {
    const int rr = L >> 2, cg = swz_cg(L);
#pragma unroll
    for (int j = 0; j < 2; ++j) {
        const int c = 2 * w + j;                 // 0..7
        const u16* src = gbase + (long)(c * 16 + rr) * stride + c0 + cg;
        gl_lds16(src, buf + c * 512);
    }
}

// ---------------- K1 (fused): weights + input-transpose + ctx-transpose -----
// k1a/k1b/k1c were three serial launches of mutually-independent work on one
// stream (two launch/drain gaps + three ramp/tail phases). Fused: one 17408-
// block launch; block ranges select the job. No numeric change.
__global__ __launch_bounds__(256) void k1_prep(const float* __restrict__ Wc,
                                               const float* __restrict__ Wcat,
                                               const float* __restrict__ input,
                                               const float* __restrict__ ctx,
                                               u16* __restrict__ Wc_hi,
                                               u16* __restrict__ Wc_lo,
                                               u16* __restrict__ Wcat_bf,
                                               u16* __restrict__ T_hi,
                                               u16* __restrict__ T_lo,
                                               u16* __restrict__ ctxT) {
    __shared__ float ts[64][33];
    const int bid = blockIdx.x;
    const int tid = threadIdx.x;

    if (bid < 3072) {
        // ---- k1a: weights -> bf16 (Wc hi/lo, Wcat plain)
        int i = bid * 256 + tid;
        if (i < IDF * CDF) {
            float f = Wc[i];
            u16 h = f2bf(f);
            Wc_hi[i] = h;
            Wc_lo[i] = f2bf(f - bf2f(h));
        } else {
            int j = i - IDF * CDF;
            Wcat_bf[j] = f2bf(Wcat[j]);
        }
        return;
    }
    if (bid < 3072 + 4096) {
        // ---- k1b: input [B,idf,Q] -> T_hi/T_lo [B,Q,idf] (64d x 32q tile)
        const int r = bid - 3072;
        const int qt = r & 31, dt = (r >> 5) & 3, b = r >> 7;
        {
            const int dl = tid >> 2, q0 = (tid & 3) * 8;
            const float* src = input + ((long)(b * IDF + dt * 64 + dl)) * QSZ + qt * 32 + q0;
            float4 v0 = *(const float4*)src;
            float4 v1 = *(const float4*)(src + 4);
            ts[dl][q0 + 0] = v0.x; ts[dl][q0 + 1] = v0.y;
            ts[dl][q0 + 2] = v0.z; ts[dl][q0 + 3] = v0.w;
            ts[dl][q0 + 4] = v1.x; ts[dl][q0 + 5] = v1.y;
            ts[dl][q0 + 6] = v1.z; ts[dl][q0 + 7] = v1.w;
        }
        __syncthreads();
        {
            const int ql = tid >> 3, d8 = (tid & 7) * 8;
            u16 hi[8], lo[8];
#pragma unroll
            for (int i = 0; i < 8; ++i) {
                float f = ts[d8 + i][ql];
                hi[i] = f2bf(f);
                lo[i] = f2bf(f - bf2f(hi[i]));
            }
            const long o = ((long)(b * QSZ + qt * 32 + ql)) * IDF + dt * 64 + d8;
            *(uint4*)(T_hi + o) = *(const uint4*)hi;
            *(uint4*)(T_lo + o) = *(const uint4*)lo;
        }
        return;
    }
    // ---- k1c: contexts [n,b,c,l] -> ctxT bf16 [n,b,l,c] (64c x 32l tile)
    {
        const int r = bid - (3072 + 4096);
        const int lt = r & 3, ct = (r >> 2) & 7, nb = r >> 5;
        const long ib = (long)nb * CDF * LSZ;
        {
            const int cl = tid >> 2, l0 = (tid & 3) * 8;
            const float* src = ctx + ib + (long)(ct * 64 + cl) * LSZ + lt * 32 + l0;
            float4 v0 = *(const float4*)src;
            float4 v1 = *(const float4*)(src + 4);
            ts[cl][l0 + 0] = v0.x; ts[cl][l0 + 1] = v0.y;
            ts[cl][l0 + 2] = v0.z; ts[cl][l0 + 3] = v0.w;
            ts[cl][l0 + 4] = v1.x; ts[cl][l0 + 5] = v1.y;
            ts[cl][l0 + 6] = v1.z; ts[cl][l0 + 7] = v1.w;
        }
        __syncthreads();
        {
            const int ll = tid >> 3, c8 = (tid & 7) * 8;
            u16 o8[8];
#pragma unroll
            for (int i = 0; i < 8; ++i) o8[i] = f2bf(ts[c8 + i][ll]);
            const long ob = (long)nb * LSZ * CDF;
            *(uint4*)(ctxT + ob + (long)(lt * 32 + ll) * CDF + ct * 64 + c8) =
                *(const uint4*)o8;
        }
    }
}

// ---------------- K2: sourceT = Wc @ ctx  (per (n,b), hi/lo x hi) ------------
// LDS-staged B tile, counted vmcnt(2), pre-swizzled source (round-7 verified).
__global__ __launch_bounds__(256, 2) void k2_src(const u16* __restrict__ Wc_hi,
                                                 const u16* __restrict__ Wc_lo,
                                                 const u16* __restrict__ ctxT,
                                                 u16* __restrict__ sTT_hi,
                                                 u16* __restrict__ sTT_lo,
                                                 u16* __restrict__ s_dl) {
    __shared__ u16 bounce[128 * 136];
    __shared__ __align__(16) u16 BST[2][4096];   // 2 x 8KB B tiles
    const int tid = threadIdx.x;
    const int L = tid & 63, w = tid >> 6;
    const int wd = w >> 1, wl = w & 1, lr = L & 15, quad = L >> 4;
    const int dbase = blockIdx.x * 128;
    const int nb = blockIdx.y;
    const u16* ctxb = ctxT + (long)nb * LSZ * CDF;

    const f32x4 vz = {0.f, 0.f, 0.f, 0.f};
    f32x4 acc[4][4];
#pragma unroll
    for (int m = 0; m < 4; ++m)
#pragma unroll
        for (int nn = 0; nn < 4; ++nn) acc[m][nn] = vz;

    // prologue: stage kc=0 B tile
    stage_128(BST[0], ctxb, CDF, 0, w, L);

    for (int kc = 0; kc < 16; ++kc) {
        const int cur = kc & 1;
        const int c0 = kc * 32 + quad * 8;
        bf16x8 aH[4], aL[4];
#pragma unroll
        for (int m = 0; m < 4; ++m) {
            const int d = dbase + 64 * wd + 16 * m + lr;
            aH[m] = ldg16(Wc_hi + d * CDF + c0);
            aL[m] = ldg16(Wc_lo + d * CDF + c0);
        }
        asm volatile("" ::: "memory");          // A-loads issue before STAGE (vm order)
        if (kc < 15) {
            stage_128(BST[cur ^ 1], ctxb, CDF, (kc + 1) * 32, w, L);
            vm_wait2();                          // retire prev-stage + A; keep 2 in flight
        } else {
            vm_wait0();                          // last step: drain (once)
        }
        mid_bar();

        bf16x8 bb[4];
#pragma unroll
        for (int nn = 0; nn < 4; ++nn)
            bb[nn] = lds16(BST[cur] + swz_off(64 * wl + 16 * nn + lr, quad));
#pragma unroll
        for (int m = 0; m < 4; ++m)
#pragma unroll
            for (int nn = 0; nn < 4; ++nn) {
                acc[m][nn] = mfma16(aH[m], bb[nn], acc[m][nn]);
                acc[m][nn] = mfma16(aL[m], bb[nn], acc[m][nn]);
            }
        end_bar();                               // reads retired before next overwrite
    }

    // ---- epilogue: 3 LDS-bounce passes for coalesced stores ----
#pragma unroll
    for (int m = 0; m < 4; ++m)
#pragma unroll
        for (int nn = 0; nn < 4; ++nn)
#pragma unroll
            for (int r = 0; r < 4; ++r) {
                const int d = 64 * wd + 16 * m + 4 * quad + r;
                const int l = 64 * wl + 16 * nn + lr;
                bounce[l * 136 + d] = f2bf(acc[m][nn][r]);
            }
    __syncthreads();
    for (int i = tid; i < 2048; i += 256) {
        const int l = i >> 4, g = (i & 15) * 8;
        *(uint4*)(sTT_hi + ((long)nb * LSZ + l) * IDF + dbase + g) =
            *(const uint4*)(bounce + l * 136 + g);
    }
    __syncthreads();
#pragma unroll
    for (int m = 0; m < 4; ++m)
#pragma unroll
        for (int nn = 0; nn < 4; ++nn)
#pragma unroll
            for (int r = 0; r < 4; ++r) {
                const int d = 64 * wd + 16 * m + 4 * quad + r;
                const int l = 64 * wl + 16 * nn + lr;
                float c = acc[m][nn][r];
                u16 h = f2bf(c);
                bounce[l * 136 + d] = f2bf(c - bf2f(h));
            }
    __syncthreads();
    for (int i = tid; i < 2048; i += 256) {
        const int l = i >> 4, g = (i & 15) * 8;
        *(uint4*)(sTT_lo + ((long)nb * LSZ + l) * IDF + dbase + g) =
            *(const uint4*)(bounce + l * 136 + g);
    }
    __syncthreads();
#pragma unroll
    for (int m = 0; m < 4; ++m)
#pragma unroll
        for (int nn = 0; nn < 4; ++nn)
#pragma unroll
            for (int r = 0; r < 4; ++r) {
                const int d = 64 * wd + 16 * m + 4 * quad + r;
                const int l = 64 * wl + 16 * nn + lr;
                bounce[d * 136 + l] = f2bf(acc[m][nn][r]);
            }
    __syncthreads();
    for (int i = tid; i < 2048; i += 256) {
        const int d = i >> 4, g = (i & 15) * 8;
        *(uint4*)(s_dl + ((long)nb * IDF + dbase + d) * LSZ + g) =
            *(const uint4*)(bounce + d * 136 + g);
    }
}

// ---------------- K3: fused scores->softmax->PV->concat-proj->LN -------------
// Round-9 verified pipeline: counted vmcnt, pre-swizzled staged tiles, T1
// b-major grid, ph1 A-register double-buffer. Schedule family at its cap
// (~290us; rounds 8/9 A/B'd conflicts+setprio+A-latency: all off critical
// path). vmcnt ledger documented at each wait.
__global__ __launch_bounds__(256, 2) void k3_attn(
    const u16* __restrict__ T_hi, const u16* __restrict__ T_lo,
    const u16* __restrict__ sTT_hi, const u16* __restrict__ sTT_lo,
    const u16* __restrict__ s_dl, const u16* __restrict__ Wcat_bf,
    const float* __restrict__ Wb, const float* __restrict__ gam_p,
    const float* __restrict__ bet_p, float* __restrict__ out)
{
    __shared__ __align__(16) u16 ST[2][8192];   // 2 x 16KB staging buffers
    __shared__ float S[64 * 132];      // scores fp32; overlaid later by attn bf16 [64][264]
    __shared__ float redA[256];
    __shared__ float redB[256];
    u16* attnL = (u16*)S;

    const int tid = threadIdx.x;
    const int L = tid & 63, w = tid >> 6;
    const int wq = w >> 1, wh = w & 1, lr = L & 15, quad = L >> 4;
    const int b = blockIdx.x;                    // b fastest -> XCD = b%8 (T1)
    const int bq = b * QSZ + blockIdx.y * 64;

    const f32x4 vz = {0.f, 0.f, 0.f, 0.f};
    f32x4 x_acc[2][8];
#pragma unroll
    for (int m = 0; m < 2; ++m)
#pragma unroll
        for (int nn = 0; nn < 8; ++nn) x_acc[m][nn] = vz;

    // A-fragment double buffer (ph1): slot kc&1 holds A(kc).
    bf16x8 aHr[2][2], aLr[2][2];

    // prologue: issue A(0) then stage n=0 ph1 kc=0 tile into ST[0].
#pragma unroll
    for (int m = 0; m < 2; ++m) {
        const int ro = (bq + 32 * wq + 16 * m + lr) * IDF + quad * 8;
        aHr[0][m] = ldg16(T_hi + ro);
        aLr[0][m] = ldg16(T_lo + ro);
    }
    asm volatile("" ::: "memory");
    stage_ph1(ST[0], sTT_hi + (long)b * (LSZ * IDF), sTT_lo + (long)b * (LSZ * IDF),
              0, w, L);

    for (int n = 0; n < NCTX; ++n) {
        const int nb = n * BSZ + b;
        const u16* sttH = sTT_hi + (long)nb * (LSZ * IDF);
        const u16* sttL = sTT_lo + (long)nb * (LSZ * IDF);
        const u16* sdl  = s_dl  + (long)nb * (IDF * LSZ);
        const u16* wcat = Wcat_bf + n * IDF;

        // ---- phase 1: S[64q x 128l] = (T_hi+T_lo).(sTT_hi+sTT_lo)^T, drop lo*lo
        f32x4 s_acc[2][4];
#pragma unroll
        for (int m = 0; m < 2; ++m)
#pragma unroll
            for (int nn = 0; nn < 4; ++nn) s_acc[m][nn] = vz;

#pragma unroll
        for (int kc = 0; kc < 8; ++kc) {
            const int cur = kc & 1;
            if (kc < 7) {
                const int c1 = (kc + 1) * 32 + quad * 8;
#pragma unroll
                for (int m = 0; m < 2; ++m) {
                    const int ro = (bq + 32 * wq + 16 * m + lr) * IDF + c1;
                    aHr[(kc + 1) & 1][m] = ldg16(T_hi + ro);
                    aLr[(kc + 1) & 1][m] = ldg16(T_lo + ro);
                }
                asm volatile("" ::: "memory");  // A-issue before stage (vm order)
                stage_ph1(ST[cur ^ 1], sttH, sttL, (kc + 1) * 32, w, L);
                vm_wait8();                      // retire A(kc)+stage(kc)
            } else {
                stage_256(ST[cur ^ 1], sdl, LSZ, 0, w, L);   // pre-stage ph2 kc0
                vm_wait4();                      // retire A(7)+stage(7)
            }
            mid_bar();

            const u16* Bh = ST[cur];
            const u16* Bl = ST[cur] + 4096;
            bf16x8 bH[4], bL[4];
#pragma unroll
            for (int nn = 0; nn < 4; ++nn) {
                const int off = swz_off(64 * wh + 16 * nn + lr, quad);
                bH[nn] = lds16(Bh + off);
                bL[nn] = lds16(Bl + off);
            }
#pragma unroll
            for (int m = 0; m < 2; ++m)
#pragma unroll
                for (int nn = 0; nn < 4; ++nn) {
                    s_acc[m][nn] = mfma16(aHr[cur][m], bH[nn], s_acc[m][nn]);
                    s_acc[m][nn] = mfma16(aHr[cur][m], bL[nn], s_acc[m][nn]);
                    s_acc[m][nn] = mfma16(aLr[cur][m], bH[nn], s_acc[m][nn]);
                }
            end_bar();                           // reads retired before next overwrite
        }

#pragma unroll
        for (int m = 0; m < 2; ++m)
#pragma unroll
            for (int nn = 0; nn < 4; ++nn)
#pragma unroll
                for (int r = 0; r < 4; ++r)
                    S[(32 * wq + 16 * m + 4 * quad + r) * 132 + 64 * wh + 16 * nn + lr] =
                        s_acc[m][nn][r];
        lg_bar();

        // ---- softmax over l (per row, 4 threads/row); keep UNNORMALIZED exp in S
        {
            const int row = tid >> 2, sg = (tid & 3) * 32;
            float* sp = S + row * 132 + sg;
            float mx = sp[0];
#pragma unroll
            for (int i = 1; i < 32; ++i) mx = fmaxf(mx, sp[i]);
            redA[row * 4 + (tid & 3)] = mx;
            lg_bar();
            const float rm = fmaxf(fmaxf(redA[row * 4], redA[row * 4 + 1]),
                                   fmaxf(redA[row * 4 + 2], redA[row * 4 + 3]));
            float sm = 0.f;
#pragma unroll
            for (int i = 0; i < 32; ++i) {
                float e = __expf(sp[i] - rm);
                sp[i] = e;
                sm += e;
            }
            redB[row * 4 + (tid & 3)] = sm;
            lg_bar();
        }

        // ---- phase 2: attn[64q x 256d] = E . s_dl^T  (unnormalized)
        f32x4 a_acc[2][8];
#pragma unroll
        for (int m = 0; m < 2; ++m)
#pragma unroll
            for (int nn = 0; nn < 8; ++nn) a_acc[m][nn] = vz;

        for (int kc = 0; kc < 4; ++kc) {
            const int cur = kc & 1;
            if (kc < 3) stage_256(ST[cur ^ 1], sdl, LSZ, (kc + 1) * 32, w, L);
            else        stage_256(ST[cur ^ 1], wcat, NCTX * IDF, 0, w, L); // pre-stage ph3 kc0
            vm_wait4();
            mid_bar();

            const int l0 = kc * 32 + quad * 8;
            bf16x8 af[2];
#pragma unroll
            for (int m = 0; m < 2; ++m)
                af[m] = pack8(S + (32 * wq + 16 * m + lr) * 132 + l0);
            const u16* Bd = ST[cur];
#pragma unroll
            for (int nn = 0; nn < 8; ++nn) {
                const int off = swz_off(128 * wh + 16 * nn + lr, quad);
                bf16x8 bf = lds16(Bd + off);
#pragma unroll
                for (int m = 0; m < 2; ++m)
                    a_acc[m][nn] = mfma16(af[m], bf, a_acc[m][nn]);
            }
            end_bar();
        }

        float invr[2][4];
#pragma unroll
        for (int m = 0; m < 2; ++m)
#pragma unroll
            for (int r = 0; r < 4; ++r) {
                const int row = 32 * wq + 16 * m + 4 * quad + r;
                invr[m][r] = 1.0f / (redB[row * 4] + redB[row * 4 + 1] +
                                     redB[row * 4 + 2] + redB[row * 4 + 3]);
            }
#pragma unroll
        for (int m = 0; m < 2; ++m)
#pragma unroll
            for (int nn = 0; nn < 8; ++nn)
#pragma unroll
                for (int r = 0; r < 4; ++r) {
                    const int row = 32 * wq + 16 * m + 4 * quad + r;
                    const int col = 128 * wh + 16 * nn + lr;
                    attnL[row * 264 + col] = f2bf(a_acc[m][nn][r] * invr[m][r]);
                }
        lg_bar();

        // ---- phase 3: X[64q x 256e] += attn . Wcat_n^T
        for (int kc = 0; kc < 8; ++kc) {
            const int cur = kc & 1;
            if (kc < 7) {
                stage_256(ST[cur ^ 1], wcat, NCTX * IDF, (kc + 1) * 32, w, L);
                vm_wait4();
            } else if (n < NCTX - 1) {
                // issue next-n A(0) then next-n ph1 kc0 stage
#pragma unroll
                for (int m = 0; m < 2; ++m) {
                    const int ro = (bq + 32 * wq + 16 * m + lr) * IDF + quad * 8;
                    aHr[0][m] = ldg16(T_hi + ro);
                    aLr[0][m] = ldg16(T_lo + ro);
                }
                asm volatile("" ::: "memory");
                const u16* nH = sTT_hi + (long)((n + 1) * BSZ + b) * (LSZ * IDF);
                const u16* nL = sTT_lo + (long)((n + 1) * BSZ + b) * (LSZ * IDF);
                stage_ph1(ST[cur ^ 1], nH, nL, 0, w, L);
                vm_wait8();                      // retire stage(7); keep A(0)+stage_ph1
            } else {
                vm_wait0();                      // true last step: drain stage(7)
            }
            mid_bar();

            const int d0 = kc * 32 + quad * 8;
            bf16x8 af[2];
#pragma unroll
            for (int m = 0; m < 2; ++m) {
                U4V t;
                t.u = *(const uint4*)(attnL + (32 * wq + 16 * m + lr) * 264 + d0);
                af[m] = t.v;
            }
            const u16* Wt = ST[cur];
#pragma unroll
            for (int nn = 0; nn < 8; ++nn) {
                const int off = swz_off(128 * wh + 16 * nn + lr, quad);
                bf16x8 bf = lds16(Wt + off);
#pragma unroll
                for (int m = 0; m < 2; ++m)
                    x_acc[m][nn] = mfma16(af[m], bf, x_acc[m][nn]);
            }
            end_bar();
        }
    }
    vm_wait0();   // safety drain (no-op in steady exit)

    // ---- epilogue: bias + relu + residual + LayerNorm(eps=0) ----
    float gv[8], bv[8], wv[8];
    int ec[8];
#pragma unroll
    for (int nn = 0; nn < 8; ++nn) {
        ec[nn] = 128 * wh + 16 * nn + lr;
        wv[nn] = Wb[ec[nn]];
        gv[nn] = gam_p[ec[nn]];
        bv[nn] = bet_p[ec[nn]];
    }
#pragma unroll
    for (int m = 0; m < 2; ++m)
#pragma unroll
        for (int r = 0; r < 4; ++r) {
            const int row = 32 * wq + 16 * m + 4 * quad + r;
            const u16* th = T_hi + (long)(bq + row) * IDF;
            const u16* tl = T_lo + (long)(bq + row) * IDF;
#pragma unroll
            for (int nn = 0; nn < 8; ++nn) {
                float resid = bf2f(th[ec[nn]]) + bf2f(tl[ec[nn]]);   // ~fp32-exact target
                x_acc[m][nn][r] = fmaxf(x_acc[m][nn][r] + wv[nn], 0.f) + resid;
            }
        }
    float s1[2][4], s2[2][4];
#pragma unroll
    for (int m = 0; m < 2; ++m)
#pragma unroll
        for (int r = 0; r < 4; ++r) {
            float a = 0.f, q2 = 0.f;
#pragma unroll
            for (int nn = 0; nn < 8; ++nn) {
                float v = x_acc[m][nn][r];
                a += v;
                q2 += v * v;
            }
            s1[m][r] = a;
            s2[m][r] = q2;
        }
#pragma unroll
    for (int off = 1; off <= 8; off <<= 1)
#pragma unroll
        for (int m = 0; m < 2; ++m)
#pragma unroll
            for (int r = 0; r < 4; ++r) {
                s1[m][r] += __shfl_xor(s1[m][r], off);
                s2[m][r] += __shfl_xor(s2[m][r], off);
            }
    if (lr == 0) {
#pragma unroll
        for (int m = 0; m < 2; ++m)
#pragma unroll
            for (int r = 0; r < 4; ++r) {
                const int row = 32 * wq + 16 * m + 4 * quad + r;
                redA[row * 4 + wh * 2]     = s1[m][r];
                redA[row * 4 + wh * 2 + 1] = s2[m][r];
            }
    }
    __syncthreads();
#pragma unroll
    for (int m = 0; m < 2; ++m)
#pragma unroll
        for (int r = 0; r < 4; ++r) {
            const int row = 32 * wq + 16 * m + 4 * quad + r;
            const float S1 = redA[row * 4] + redA[row * 4 + 2];
            const float S2 = redA[row * 4 + 1] + redA[row * 4 + 3];
            const float mu = S1 * (1.f / 256.f);
            const float rs = rsqrtf(S2 * (1.f / 256.f) - mu * mu);
            float* op = out + (long)(bq + row) * IDF;
#pragma unroll
            for (int nn = 0; nn < 8; ++nn)
                op[ec[nn]] = (x_acc[m][nn][r] - mu) * rs * gv[nn] + bv[nn];
        }
}

// ---------------- launch ----------------
extern "C" void kernel_launch(void* const* d_in, const int* in_sizes, int n_in,
                              void* d_out, int out_size, void* d_ws, size_t ws_size,
                              hipStream_t stream) {
    const float* input    = (const float*)d_in[0];
    const float* contexts = (const float*)d_in[1];
    const float* Wc       = (const float*)d_in[2];
    const float* Wcat     = (const float*)d_in[3];
    const float* Wb       = (const float*)d_in[4];
    const float* gamma    = (const float*)d_in[5];
    const float* beta     = (const float*)d_in[6];
    float* out = (float*)d_out;

    char* ws = (char*)d_ws;
    size_t off = 0;
    u16* Wc_hi   = (u16*)(ws + off); off += (size_t)IDF * CDF * 2;          // 256 KB
    u16* Wc_lo   = (u16*)(ws + off); off += (size_t)IDF * CDF * 2;          // 256 KB
    u16* Wcat_bf = (u16*)(ws + off); off += (size_t)IDF * NCTX * IDF * 2;   // 1.25 MB
    u16* T_hi    = (u16*)(ws + off); off += (size_t)BSZ * QSZ * IDF * 2;    // 16.8 MB
    u16* T_lo    = (u16*)(ws + off); off += (size_t)BSZ * QSZ * IDF * 2;    // 16.8 MB
    u16* ctxT    = (u16*)(ws + off); off += (size_t)NCTX * BSZ * LSZ * CDF * 2; // 41.9 MB
    u16* sTT_hi  = (u16*)(ws + off); off += (size_t)NCTX * BSZ * LSZ * IDF * 2; // 21.0 MB
    u16* sTT_lo  = (u16*)(ws + off); off += (size_t)NCTX * BSZ * LSZ * IDF * 2; // 21.0 MB
    u16* s_dl    = (u16*)(ws + off); off += (size_t)NCTX * BSZ * IDF * LSZ * 2; // 21.0 MB
    (void)in_sizes; (void)n_in; (void)out_size; (void)ws_size;

    // fused prep: 3072 (k1a) + 4096 (k1b) + 10240 (k1c) blocks
    k1_prep<<<17408, 256, 0, stream>>>(Wc, Wcat, input, contexts,
                                       Wc_hi, Wc_lo, Wcat_bf, T_hi, T_lo, ctxT);
    k2_src<<<dim3(2, NCTX * BSZ), 256, 0, stream>>>(Wc_hi, Wc_lo, ctxT, sTT_hi, sTT_lo, s_dl);
    k3_attn<<<dim3(BSZ, QSZ / 64), 256, 0, stream>>>(T_hi, T_lo, sTT_hi, sTT_lo, s_dl,
                                                     Wcat_bf, Wb, gamma, beta, out);
}

// Round 11
// 482.953 us; speedup vs baseline: 1.0781x; 1.0452x over previous
//
#include <hip/hip_runtime.h>
#include <cstdint>

typedef unsigned short u16;
typedef unsigned int   u32;
typedef __bf16 bf16x8 __attribute__((ext_vector_type(8)));
typedef float  f32x4  __attribute__((ext_vector_type(4)));

#define NCTX 10
#define BSZ  32
#define IDF  256
#define QSZ  1024
#define CDF  512
#define LSZ  128

__device__ __forceinline__ u16 f2bf(float f) {
    u32 u = __float_as_uint(f);
    u += 0x7FFFu + ((u >> 16) & 1u);          // RNE to bf16
    return (u16)(u >> 16);
}
__device__ __forceinline__ float bf2f(u16 h) {
    return __uint_as_float(((u32)h) << 16);
}

union U4V { uint4 u; bf16x8 v; };

__device__ __forceinline__ bf16x8 ldg16(const u16* p) {   // 8 contiguous bf16 (16B)
    U4V t; t.u = *(const uint4*)p; return t.v;
}
__device__ __forceinline__ bf16x8 lds16(const u16* p) {   // 8 bf16 from LDS (ds_read_b128)
    U4V t; t.u = *(const uint4*)p; return t.v;
}
__device__ __forceinline__ bf16x8 pack8(const float* f) { // 8 f32 -> bf16x8 (RNE)
    U4V t;
    t.u.x = (u32)f2bf(f[0]) | ((u32)f2bf(f[1]) << 16);
    t.u.y = (u32)f2bf(f[2]) | ((u32)f2bf(f[3]) << 16);
    t.u.z = (u32)f2bf(f[4]) | ((u32)f2bf(f[5]) << 16);
    t.u.w = (u32)f2bf(f[6]) | ((u32)f2bf(f[7]) << 16);
    return t.v;
}
__device__ __forceinline__ f32x4 mfma16(bf16x8 a, bf16x8 b, f32x4 c) {
    return __builtin_amdgcn_mfma_f32_16x16x32_bf16(a, b, c, 0, 0, 0);
}

// async global->LDS, 16B per lane; LDS dest is wave-uniform base + lane*16
__device__ __forceinline__ void gl_lds16(const u16* g, u16* l) {
    __builtin_amdgcn_global_load_lds(
        (__attribute__((address_space(1))) void*)(g),
        (__attribute__((address_space(3))) void*)(l), 16, 0, 0);
}

// ---- sync primitives (counted-vmcnt pipeline; never drain vm in the k-loop)
__device__ __forceinline__ void vm_wait4() {
    asm volatile("s_waitcnt vmcnt(4)" ::: "memory");
    __builtin_amdgcn_sched_barrier(0);
}
__device__ __forceinline__ void vm_wait2() {
    asm volatile("s_waitcnt vmcnt(2)" ::: "memory");
    __builtin_amdgcn_sched_barrier(0);
}
__device__ __forceinline__ void vm_wait0() {
    asm volatile("s_waitcnt vmcnt(0)" ::: "memory");
    __builtin_amdgcn_sched_barrier(0);
}
__device__ __forceinline__ void mid_bar()  {
    __builtin_amdgcn_s_barrier();
    asm volatile("" ::: "memory");
}
__device__ __forceinline__ void end_bar()  {
    asm volatile("" ::: "memory");
    __builtin_amdgcn_s_barrier();
    asm volatile("" ::: "memory");
}
__device__ __forceinline__ void lg_bar()   {   // LDS-visibility barrier, no vm drain
    asm volatile("s_waitcnt lgkmcnt(0)" ::: "memory");
    __builtin_amdgcn_sched_barrier(0);
    __builtin_amdgcn_s_barrier();
    asm volatile("" ::: "memory");
}

// ---- staging helpers ----
// Tiles row-major [rows][32] bf16 (64B rows), staged in 1KB chunks of 16 rows.
// Bank swizzle (T2 via pre-swizzled SOURCE, m173): LDS slot (L&3) of row
// rr=L>>2 holds global colgroup ((L&3)+(rr>>1))&3. Reader inverts. (8-way
// conflict without it: 21M cycles round 4 -> 7.9M round 6.)
__device__ __forceinline__ int swz_cg(int L) {
    return (((L & 3) + ((L >> 3) & 3)) & 3) * 8;     // element offset of source colgroup
}
__device__ __forceinline__ int swz_off(int row, int quad) {
    return row * 32 + ((quad - (row >> 1)) & 3) * 8; // element offset for reader
}

// ---- 4-wave variants (k2) ----
// ph1-style 128-row tile into 8KB (k2 B tile): 2 chunks/wave over 4 waves
__device__ __forceinline__ void stage_128_w4(u16* buf, const u16* gbase, int stride,
                                             int c0, int w, int L) {
    const int rr = L >> 2, cg = swz_cg(L);
#pragma unroll
    for (int j = 0; j < 2; ++j) {
        const int c = 2 * w + j;                 // 0..7
        const u16* src = gbase + (long)(c * 16 + rr) * stride + c0 + cg;
        gl_lds16(src, buf + c * 512);
    }
}

// ---- 8-wave variants (k3, 512 threads): 16 chunks, 2 per wave -> 2 vm-ops
// ph1 tile: Bh[128][32] at buf[0..4095], Bl[128][32] at buf[4096..8191]
__device__ __forceinline__ void stage_ph1_w8(u16* buf, const u16* sttH, const u16* sttL,
                                             int c0, int w, int L) {
    const int rr = L >> 2, cg = swz_cg(L);
#pragma unroll
    for (int j = 0; j < 2; ++j) {
        const int c = 2 * w + j;                 // 0..15, wave-uniform
        const int hi = (c < 8);
        const int ch = hi ? c : c - 8;
        const u16* src = (hi ? sttH : sttL) + (long)(ch * 16 + rr) * IDF + c0 + cg;
        gl_lds16(src, buf + (hi ? 0 : 4096) + ch * 512);
    }
}

// 256-row tile [256][32] filling a 16KB buffer
__device__ __forceinline__ void stage_256_w8(u16* buf, const u16* gbase, int stride,
                                             int c0, int w, int L) {
    const int rr = L >> 2, cg = swz_cg(L);
#pragma unroll
    for (int j = 0; j < 2; ++j) {
        const int c = 2 * w + j;                 // 0..15
        const u16* src = gbase + (long)(c * 16 + rr) * stride + c0 + cg;
        gl_lds16(src, buf + c * 512);
    }
}

// ---------------- K1 (fused): weights + input-transpose + ctx-transpose -----
__global__ __launch_bounds__(256) void k1_prep(const float* __restrict__ Wc,
                                               const float* __restrict__ Wcat,
                                               const float* __restrict__ input,
                                               const float* __restrict__ ctx,
                                               u16* __restrict__ Wc_hi,
                                               u16* __restrict__ Wc_lo,
                                               u16* __restrict__ Wcat_bf,
                                               u16* __restrict__ T_hi,
                                               u16* __restrict__ T_lo,
                                               u16* __restrict__ ctxT) {
    __shared__ float ts[64][33];
    const int bid = blockIdx.x;
    const int tid = threadIdx.x;

    if (bid < 3072) {
        int i = bid * 256 + tid;
        if (i < IDF * CDF) {
            float f = Wc[i];
            u16 h = f2bf(f);
            Wc_hi[i] = h;
            Wc_lo[i] = f2bf(f - bf2f(h));
        } else {
            int j = i - IDF * CDF;
            Wcat_bf[j] = f2bf(Wcat[j]);
        }
        return;
    }
    if (bid < 3072 + 4096) {
        const int r = bid - 3072;
        const int qt = r & 31, dt = (r >> 5) & 3, b = r >> 7;
        {
            const int dl = tid >> 2, q0 = (tid & 3) * 8;
            const float* src = input + ((long)(b * IDF + dt * 64 + dl)) * QSZ + qt * 32 + q0;
            float4 v0 = *(const float4*)src;
            float4 v1 = *(const float4*)(src + 4);
            ts[dl][q0 + 0] = v0.x; ts[dl][q0 + 1] = v0.y;
            ts[dl][q0 + 2] = v0.z; ts[dl][q0 + 3] = v0.w;
            ts[dl][q0 + 4] = v1.x; ts[dl][q0 + 5] = v1.y;
            ts[dl][q0 + 6] = v1.z; ts[dl][q0 + 7] = v1.w;
        }
        __syncthreads();
        {
            const int ql = tid >> 3, d8 = (tid & 7) * 8;
            u16 hi[8], lo[8];
#pragma unroll
            for (int i = 0; i < 8; ++i) {
                float f = ts[d8 + i][ql];
                hi[i] = f2bf(f);
                lo[i] = f2bf(f - bf2f(hi[i]));
            }
            const long o = ((long)(b * QSZ + qt * 32 + ql)) * IDF + dt * 64 + d8;
            *(uint4*)(T_hi + o) = *(const uint4*)hi;
            *(uint4*)(T_lo + o) = *(const uint4*)lo;
        }
        return;
    }
    {
        const int r = bid - (3072 + 4096);
        const int lt = r & 3, ct = (r >> 2) & 7, nb = r >> 5;
        const long ib = (long)nb * CDF * LSZ;
        {
            const int cl = tid >> 2, l0 = (tid & 3) * 8;
            const float* src = ctx + ib + (long)(ct * 64 + cl) * LSZ + lt * 32 + l0;
            float4 v0 = *(const float4*)src;
            float4 v1 = *(const float4*)(src + 4);
            ts[cl][l0 + 0] = v0.x; ts[cl][l0 + 1] = v0.y;
            ts[cl][l0 + 2] = v0.z; ts[cl][l0 + 3] = v0.w;
            ts[cl][l0 + 4] = v1.x; ts[cl][l0 + 5] = v1.y;
            ts[cl][l0 + 6] = v1.z; ts[cl][l0 + 7] = v1.w;
        }
        __syncthreads();
        {
            const int ll = tid >> 3, c8 = (tid & 7) * 8;
            u16 o8[8];
#pragma unroll
            for (int i = 0; i < 8; ++i) o8[i] = f2bf(ts[c8 + i][ll]);
            const long ob = (long)nb * LSZ * CDF;
            *(uint4*)(ctxT + ob + (long)(lt * 32 + ll) * CDF + ct * 64 + c8) =
                *(const uint4*)o8;
        }
    }
}

// ---------------- K2: sourceT = Wc @ ctx  (per (n,b), hi/lo x hi) ------------
// LDS-staged B tile, counted vmcnt(2), pre-swizzled source (round-7 verified).
__global__ __launch_bounds__(256, 2) void k2_src(const u16* __restrict__ Wc_hi,
                                                 const u16* __restrict__ Wc_lo,
                                                 const u16* __restrict__ ctxT,
                                                 u16* __restrict__ sTT_hi,
                                                 u16* __restrict__ sTT_lo,
                                                 u16* __restrict__ s_dl) {
    __shared__ u16 bounce[128 * 136];
    __shared__ __align__(16) u16 BST[2][4096];   // 2 x 8KB B tiles
    const int tid = threadIdx.x;
    const int L = tid & 63, w = tid >> 6;
    const int wd = w >> 1, wl = w & 1, lr = L & 15, quad = L >> 4;
    const int dbase = blockIdx.x * 128;
    const int nb = blockIdx.y;
    const u16* ctxb = ctxT + (long)nb * LSZ * CDF;

    const f32x4 vz = {0.f, 0.f, 0.f, 0.f};
    f32x4 acc[4][4];
#pragma unroll
    for (int m = 0; m < 4; ++m)
#pragma unroll
        for (int nn = 0; nn < 4; ++nn) acc[m][nn] = vz;

    // prologue: stage kc=0 B tile
    stage_128_w4(BST[0], ctxb, CDF, 0, w, L);

    for (int kc = 0; kc < 16; ++kc) {
        const int cur = kc & 1;
        const int c0 = kc * 32 + quad * 8;
        bf16x8 aH[4], aL[4];
#pragma unroll
        for (int m = 0; m < 4; ++m) {
            const int d = dbase + 64 * wd + 16 * m + lr;
            aH[m] = ldg16(Wc_hi + d * CDF + c0);
            aL[m] = ldg16(Wc_lo + d * CDF + c0);
        }
        asm volatile("" ::: "memory");          // A-loads issue before STAGE (vm order)
        if (kc < 15) {
            stage_128_w4(BST[cur ^ 1], ctxb, CDF, (kc + 1) * 32, w, L);
            vm_wait2();                          // retire prev-stage + A; keep 2 in flight
        } else {
            vm_wait0();                          // last step: drain (once)
        }
        mid_bar();

        bf16x8 bb[4];
#pragma unroll
        for (int nn = 0; nn < 4; ++nn)
            bb[nn] = lds16(BST[cur] + swz_off(64 * wl + 16 * nn + lr, quad));
#pragma unroll
        for (int m = 0; m < 4; ++m)
#pragma unroll
            for (int nn = 0; nn < 4; ++nn) {
                acc[m][nn] = mfma16(aH[m], bb[nn], acc[m][nn]);
                acc[m][nn] = mfma16(aL[m], bb[nn], acc[m][nn]);
            }
        end_bar();                               // reads retired before next overwrite
    }

    // ---- epilogue: 3 LDS-bounce passes for coalesced stores ----
#pragma unroll
    for (int m = 0; m < 4; ++m)
#pragma unroll
        for (int nn = 0; nn < 4; ++nn)
#pragma unroll
            for (int r = 0; r < 4; ++r) {
                const int d = 64 * wd + 16 * m + 4 * quad + r;
                const int l = 64 * wl + 16 * nn + lr;
                bounce[l * 136 + d] = f2bf(acc[m][nn][r]);
            }
    __syncthreads();
    for (int i = tid; i < 2048; i += 256) {
        const int l = i >> 4, g = (i & 15) * 8;
        *(uint4*)(sTT_hi + ((long)nb * LSZ + l) * IDF + dbase + g) =
            *(const uint4*)(bounce + l * 136 + g);
    }
    __syncthreads();
#pragma unroll
    for (int m = 0; m < 4; ++m)
#pragma unroll
        for (int nn = 0; nn < 4; ++nn)
#pragma unroll
            for (int r = 0; r < 4; ++r) {
                const int d = 64 * wd + 16 * m + 4 * quad + r;
                const int l = 64 * wl + 16 * nn + lr;
                float c = acc[m][nn][r];
                u16 h = f2bf(c);
                bounce[l * 136 + d] = f2bf(c - bf2f(h));
            }
    __syncthreads();
    for (int i = tid; i < 2048; i += 256) {
        const int l = i >> 4, g = (i & 15) * 8;
        *(uint4*)(sTT_lo + ((long)nb * LSZ + l) * IDF + dbase + g) =
            *(const uint4*)(bounce + l * 136 + g);
    }
    __syncthreads();
#pragma unroll
    for (int m = 0; m < 4; ++m)
#pragma unroll
        for (int nn = 0; nn < 4; ++nn)
#pragma unroll
            for (int r = 0; r < 4; ++r) {
                const int d = 64 * wd + 16 * m + 4 * quad + r;
                const int l = 64 * wl + 16 * nn + lr;
                bounce[d * 136 + l] = f2bf(acc[m][nn][r]);
            }
    __syncthreads();
    for (int i = tid; i < 2048; i += 256) {
        const int d = i >> 4, g = (i & 15) * 8;
        *(uint4*)(s_dl + ((long)nb * IDF + dbase + d) * LSZ + g) =
            *(const uint4*)(bounce + d * 136 + g);
    }
}

// ---------------- K3: fused scores->softmax->PV->concat-proj->LN -------------
// Round-9 pipeline re-hosted on 512 threads / 8 waves (wq 0..3 16-row strips,
// wh col-half). Rationale: rounds 1-3 proved >2 waves/SIMD impossible with
// REGISTER-streamed operands (~200 regs natural); since round 4 B-operands
// come from LDS -> natural footprint ~115-120 regs. (512,4) = 128-reg budget:
// alloc <=128 -> 2 blocks/CU = 16 waves/CU (2x today); alloc >128 -> 1
// block/CU = 8 waves = today (bounded downside, no spill regime).
// vmcnt ledger (2 vm-ops per stage, 2 per A): ph1 kc<7: out=[A(kc)2,st(kc)2,
// A(kc+1)2,st(kc+1)2]=8 -> wait4. ph1 kc7: out=[A7,st7,st_ph2]=6 -> wait2.
// ph2: out=[st(kc),st(kc+1)]=4 -> wait2. ph3 kc<7: wait2. ph3 kc7 n<9:
// out=[st7,A0,st_ph1]=6 -> wait4. ph3 kc7 n=9: out=[st7]=2 -> wait0.
__global__ __launch_bounds__(512, 4) void k3_attn(
    const u16* __restrict__ T_hi, const u16* __restrict__ T_lo,
    const u16* __restrict__ sTT_hi, const u16* __restrict__ sTT_lo,
    const u16* __restrict__ s_dl, const u16* __restrict__ Wcat_bf,
    const float* __restrict__ Wb, const float* __restrict__ gam_p,
    const float* __restrict__ bet_p, float* __restrict__ out)
{
    __shared__ __align__(16) u16 ST[2][8192];   // 2 x 16KB staging buffers
    __shared__ float S[64 * 132];      // scores fp32; overlaid later by attn bf16 [64][264]
    __shared__ float redA[512];
    __shared__ float redB[512];
    u16* attnL = (u16*)S;

    const int tid = threadIdx.x;
    const int L = tid & 63, w = tid >> 6;       // 8 waves
    const int wq = w >> 1, wh = w & 1;          // wq 0..3, wh 0..1
    const int lr = L & 15, quad = L >> 4;
    const int b = blockIdx.x;                    // b fastest -> XCD = b%8 (T1)
    const int bq = b * QSZ + blockIdx.y * 64;

    const f32x4 vz = {0.f, 0.f, 0.f, 0.f};
    f32x4 x_acc[8];
#pragma unroll
    for (int nn = 0; nn < 8; ++nn) x_acc[nn] = vz;

    // A-fragment double buffer (ph1): slot kc&1 holds A(kc).
    bf16x8 aHr[2], aLr[2];

    // prologue: issue A(0) then stage n=0 ph1 kc=0 tile into ST[0].
    {
        const int ro = (bq + 16 * wq + lr) * IDF + quad * 8;
        aHr[0] = ldg16(T_hi + ro);
        aLr[0] = ldg16(T_lo + ro);
    }
    asm volatile("" ::: "memory");
    stage_ph1_w8(ST[0], sTT_hi + (long)b * (LSZ * IDF), sTT_lo + (long)b * (LSZ * IDF),
                 0, w, L);

    for (int n = 0; n < NCTX; ++n) {
        const int nb = n * BSZ + b;
        const u16* sttH = sTT_hi + (long)nb * (LSZ * IDF);
        const u16* sttL = sTT_lo + (long)nb * (LSZ * IDF);
        const u16* sdl  = s_dl  + (long)nb * (IDF * LSZ);
        const u16* wcat = Wcat_bf + n * IDF;

        // ---- phase 1: S[64q x 128l] = (T_hi+T_lo).(sTT_hi+sTT_lo)^T, drop lo*lo
        // wave (wq,wh): rows 16wq..+15, cols 64wh..+63
        f32x4 s_acc[4];
#pragma unroll
        for (int nn = 0; nn < 4; ++nn) s_acc[nn] = vz;

#pragma unroll
        for (int kc = 0; kc < 8; ++kc) {
            const int cur = kc & 1;
            if (kc < 7) {
                const int c1 = (kc + 1) * 32 + quad * 8;
                {
                    const int ro = (bq + 16 * wq + lr) * IDF + c1;
                    aHr[(kc + 1) & 1] = ldg16(T_hi + ro);
                    aLr[(kc + 1) & 1] = ldg16(T_lo + ro);
                }
                asm volatile("" ::: "memory");  // A-issue before stage (vm order)
                stage_ph1_w8(ST[cur ^ 1], sttH, sttL, (kc + 1) * 32, w, L);
                vm_wait4();                      // retire A(kc)+stage(kc)
            } else {
                stage_256_w8(ST[cur ^ 1], sdl, LSZ, 0, w, L);   // pre-stage ph2 kc0
                vm_wait2();                      // retire A(7)+stage(7)
            }
            mid_bar();

            const u16* Bh = ST[cur];
            const u16* Bl = ST[cur] + 4096;
            bf16x8 bH[4], bL[4];
#pragma unroll
            for (int nn = 0; nn < 4; ++nn) {
                const int off = swz_off(64 * wh + 16 * nn + lr, quad);
                bH[nn] = lds16(Bh + off);
                bL[nn] = lds16(Bl + off);
            }
#pragma unroll
            for (int nn = 0; nn < 4; ++nn) {
                s_acc[nn] = mfma16(aHr[cur], bH[nn], s_acc[nn]);
                s_acc[nn] = mfma16(aHr[cur], bL[nn], s_acc[nn]);
                s_acc[nn] = mfma16(aLr[cur], bH[nn], s_acc[nn]);
            }
            end_bar();                           // reads retired before next overwrite
        }

#pragma unroll
        for (int nn = 0; nn < 4; ++nn)
#pragma unroll
            for (int r = 0; r < 4; ++r)
                S[(16 * wq + 4 * quad + r) * 132 + 64 * wh + 16 * nn + lr] =
                    s_acc[nn][r];
        lg_bar();

        // ---- softmax over l (per row, 8 threads/row, round-2-verified form);
        // keep UNNORMALIZED exp in S
        {
            const int row = tid >> 3, sg = (tid & 7) * 16;
            float* sp = S + row * 132 + sg;
            float mx = sp[0];
#pragma unroll
            for (int i = 1; i < 16; ++i) mx = fmaxf(mx, sp[i]);
            redA[row * 8 + (tid & 7)] = mx;
            lg_bar();
            float rm = redA[row * 8];
#pragma unroll
            for (int j = 1; j < 8; ++j) rm = fmaxf(rm, redA[row * 8 + j]);
            float sm = 0.f;
#pragma unroll
            for (int i = 0; i < 16; ++i) {
                float e = __expf(sp[i] - rm);
                sp[i] = e;
                sm += e;
            }
            redB[row * 8 + (tid & 7)] = sm;
            lg_bar();
        }

        // ---- phase 2: attn[64q x 256d] = E . s_dl^T  (unnormalized)
        // wave (wq,wh): rows 16wq..+15, cols 128wh..+127
        f32x4 a_acc[8];
#pragma unroll
        for (int nn = 0; nn < 8; ++nn) a_acc[nn] = vz;

        for (int kc = 0; kc < 4; ++kc) {
            const int cur = kc & 1;
            if (kc < 3) stage_256_w8(ST[cur ^ 1], sdl, LSZ, (kc + 1) * 32, w, L);
            else        stage_256_w8(ST[cur ^ 1], wcat, NCTX * IDF, 0, w, L); // pre-stage ph3 kc0
            vm_wait2();
            mid_bar();

            const int l0 = kc * 32 + quad * 8;
            bf16x8 af = pack8(S + (16 * wq + lr) * 132 + l0);
            const u16* Bd = ST[cur];
#pragma unroll
            for (int nn = 0; nn < 8; ++nn) {
                const int off = swz_off(128 * wh + 16 * nn + lr, quad);
                bf16x8 bf = lds16(Bd + off);
                a_acc[nn] = mfma16(af, bf, a_acc[nn]);
            }
            end_bar();
        }

        float invr[4];
#pragma unroll
        for (int r = 0; r < 4; ++r) {
            const int row = 16 * wq + 4 * quad + r;
            float sm = redB[row * 8];
#pragma unroll
            for (int j = 1; j < 8; ++j) sm += redB[row * 8 + j];
            invr[r] = 1.0f / sm;
        }
#pragma unroll
        for (int nn = 0; nn < 8; ++nn)
#pragma unroll
            for (int r = 0; r < 4; ++r) {
                const int row = 16 * wq + 4 * quad + r;
                const int col = 128 * wh + 16 * nn + lr;
                attnL[row * 264 + col] = f2bf(a_acc[nn][r] * invr[r]);
            }
        lg_bar();

        // ---- phase 3: X[64q x 256e] += attn . Wcat_n^T
        for (int kc = 0; kc < 8; ++kc) {
            const int cur = kc & 1;
            if (kc < 7) {
                stage_256_w8(ST[cur ^ 1], wcat, NCTX * IDF, (kc + 1) * 32, w, L);
                vm_wait2();
            } else if (n < NCTX - 1) {
                // issue next-n A(0) then next-n ph1 kc0 stage
                {
                    const int ro = (bq + 16 * wq + lr) * IDF + quad * 8;
                    aHr[0] = ldg16(T_hi + ro);
                    aLr[0] = ldg16(T_lo + ro);
                }
                asm volatile("" ::: "memory");
                const u16* nH = sTT_hi + (long)((n + 1) * BSZ + b) * (LSZ * IDF);
                const u16* nL = sTT_lo + (long)((n + 1) * BSZ + b) * (LSZ * IDF);
                stage_ph1_w8(ST[cur ^ 1], nH, nL, 0, w, L);
                vm_wait4();                      // retire stage(7); keep A(0)+stage_ph1
            } else {
                vm_wait0();                      // true last step: drain stage(7)
            }
            mid_bar();

            const int d0 = kc * 32 + quad * 8;
            bf16x8 af;
            {
                U4V t;
                t.u = *(const uint4*)(attnL + (16 * wq + lr) * 264 + d0);
                af = t.v;
            }
            const u16* Wt = ST[cur];
#pragma unroll
            for (int nn = 0; nn < 8; ++nn) {
                const int off = swz_off(128 * wh + 16 * nn + lr, quad);
                bf16x8 bf = lds16(Wt + off);
                x_acc[nn] = mfma16(af, bf, x_acc[nn]);
            }
            end_bar();
        }
    }
    vm_wait0();   // safety drain (no-op in steady exit)

    // ---- epilogue: bias + relu + residual + LayerNorm(eps=0) ----
    float gv[8], bv[8], wv[8];
    int ec[8];
#pragma unroll
    for (int nn = 0; nn < 8; ++nn) {
        ec[nn] = 128 * wh + 16 * nn + lr;
        wv[nn] = Wb[ec[nn]];
        gv[nn] = gam_p[ec[nn]];
        bv[nn] = bet_p[ec[nn]];
    }
#pragma unroll
    for (int r = 0; r < 4; ++r) {
        const int row = 16 * wq + 4 * quad + r;
        const u16* th = T_hi + (long)(bq + row) * IDF;
        const u16* tl = T_lo + (long)(bq + row) * IDF;
#pragma unroll
        for (int nn = 0; nn < 8; ++nn) {
            float resid = bf2f(th[ec[nn]]) + bf2f(tl[ec[nn]]);   // ~fp32-exact target
            x_acc[nn][r] = fmaxf(x_acc[nn][r] + wv[nn], 0.f) + resid;
        }
    }
    float s1[4], s2[4];
#pragma unroll
    for (int r = 0; r < 4; ++r) {
        float a = 0.f, q2 = 0.f;
#pragma unroll
        for (int nn = 0; nn < 8; ++nn) {
            float v = x_acc[nn][r];
            a += v;
            q2 += v * v;
        }
        s1[r] = a;
        s2[r] = q2;
    }
#pragma unroll
    for (int off = 1; off <= 8; off <<= 1)
#pragma unroll
        for (int r = 0; r < 4; ++r) {
            s1[r] += __shfl_xor(s1[r], off);
            s2[r] += __shfl_xor(s2[r], off);
        }
    if (lr == 0) {
#pragma unroll
        for (int r = 0; r < 4; ++r) {
            const int row = 16 * wq + 4 * quad + r;
            redA[row * 4 + wh * 2]     = s1[r];
            redA[row * 4 + wh * 2 + 1] = s2[r];
        }
    }
    __syncthreads();
#pragma unroll
    for (int r = 0; r < 4; ++r) {
        const int row = 16 * wq + 4 * quad + r;
        const float S1 = redA[row * 4] + redA[row * 4 + 2];
        const float S2 = redA[row * 4 + 1] + redA[row * 4 + 3];
        const float mu = S1 * (1.f / 256.f);
        const float rs = rsqrtf(S2 * (1.f / 256.f) - mu * mu);
        float* op = out + (long)(bq + row) * IDF;
#pragma unroll
        for (int nn = 0; nn < 8; ++nn)
            op[ec[nn]] = (x_acc[nn][r] - mu) * rs * gv[nn] + bv[nn];
    }
}

// ---------------- launch ----------------
extern "C" void kernel_launch(void* const* d_in, const int* in_sizes, int n_in,
                              void* d_out, int out_size, void* d_ws, size_t ws_size,
                              hipStream_t stream) {
    const float* input    = (const float*)d_in[0];
    const float* contexts = (const float*)d_in[1];
    const float* Wc       = (const float*)d_in[2];
    const float* Wcat     = (const float*)d_in[3];
    const float* Wb       = (const float*)d_in[4];
    const float* gamma    = (const float*)d_in[5];
    const float* beta     = (const float*)d_in[6];
    float* out = (float*)d_out;

    char* ws = (char*)d_ws;
    size_t off = 0;
    u16* Wc_hi   = (u16*)(ws + off); off += (size_t)IDF * CDF * 2;          // 256 KB
    u16* Wc_lo   = (u16*)(ws + off); off += (size_t)IDF * CDF * 2;          // 256 KB
    u16* Wcat_bf = (u16*)(ws + off); off += (size_t)IDF * NCTX * IDF * 2;   // 1.25 MB
    u16* T_hi    = (u16*)(ws + off); off += (size_t)BSZ * QSZ * IDF * 2;    // 16.8 MB
    u16* T_lo    = (u16*)(ws + off); off += (size_t)BSZ * QSZ * IDF * 2;    // 16.8 MB
    u16* ctxT    = (u16*)(ws + off); off += (size_t)NCTX * BSZ * LSZ * CDF * 2; // 41.9 MB
    u16* sTT_hi  = (u16*)(ws + off); off += (size_t)NCTX * BSZ * LSZ * IDF * 2; // 21.0 MB
    u16* sTT_lo  = (u16*)(ws + off); off += (size_t)NCTX * BSZ * LSZ * IDF * 2; // 21.0 MB
    u16* s_dl    = (u16*)(ws + off); off += (size_t)NCTX * BSZ * IDF * LSZ * 2; // 21.0 MB
    (void)in_sizes; (void)n_in; (void)out_size; (void)ws_size;

    // fused prep: 3072 (k1a) + 4096 (k1b) + 10240 (k1c) blocks
    k1_prep<<<17408, 256, 0, stream>>>(Wc, Wcat, input, contexts,
                                       Wc_hi, Wc_lo, Wcat_bf, T_hi, T_lo, ctxT);
    k2_src<<<dim3(2, NCTX * BSZ), 256, 0, stream>>>(Wc_hi, Wc_lo, ctxT, sTT_hi, sTT_lo, s_dl);
    k3_attn<<<dim3(BSZ, QSZ / 64), 512, 0, stream>>>(T_hi, T_lo, sTT_hi, sTT_lo, s_dl,
                                                     Wcat_bf, Wb, gamma, beta, out);
}